// Round 4
// baseline (1487.364 us; speedup 1.0000x reference)
//
#include <hip/hip_runtime.h>
#include <hip/hip_bf16.h>

// Problem constants (from reference)
constexpr int NN = 50000;   // nodes
constexpr int EE = 800000;  // edges
constexpr int C  = 128;     // channels (IN == H == 128)
constexpr int KC = 20;      // clusters
constexpr int NB = (NN + 1023) / 1024;   // scan blocks (49)

typedef __attribute__((ext_vector_type(8))) short bf16x8;   // 8 bf16 (4 VGPRs)
typedef __attribute__((ext_vector_type(4))) float f32x4;

__device__ inline unsigned short f2bf(float f) {            // RN f32->bf16
    unsigned u = __float_as_uint(f);
    u += 0x7fff + ((u >> 16) & 1);
    return (unsigned short)(u >> 16);
}
__device__ inline float bf2f(unsigned short h) {
    return __uint_as_float(((unsigned)h) << 16);
}

// ---------------------------------------------------------------------------
// Graph preprocessing (int inputs are int32 on device)
// ---------------------------------------------------------------------------

__global__ void k_hist(const int* __restrict__ ei, unsigned* cnt) {
    int e = blockIdx.x * 256 + threadIdx.x;
    if (e >= EE) return;
    atomicAdd(&cnt[ei[EE + e]], 1u);
}

__global__ __launch_bounds__(256) void k_scan1(const unsigned* __restrict__ cnt,
                                               unsigned* __restrict__ bsum) {
    __shared__ unsigned red[256];
    int b = blockIdx.x, t = threadIdx.x;
    int i0 = b * 1024 + t * 4;
    unsigned s = 0;
    #pragma unroll
    for (int j = 0; j < 4; ++j) { int i = i0 + j; s += (i < NN) ? cnt[i] : 0u; }
    red[t] = s; __syncthreads();
    for (int st = 128; st > 0; st >>= 1) { if (t < st) red[t] += red[t + st]; __syncthreads(); }
    if (t == 0) bsum[b] = red[0];
}

__global__ void k_scan2(unsigned* bsum, unsigned* total) {   // 1 block, 64 thr
    int t = threadIdx.x;
    unsigned v = (t < NB) ? bsum[t] : 0u;
    unsigned x = v;
    #pragma unroll
    for (int s = 1; s < 64; s <<= 1) { unsigned u = __shfl_up(x, s, 64); if (t >= s) x += u; }
    if (t < NB) bsum[t] = x - v;     // exclusive block offset
    if (t == 63) *total = x;
}

__global__ __launch_bounds__(256) void k_scan3(const unsigned* __restrict__ cnt,
                                               const unsigned* __restrict__ bsum,
                                               const unsigned* __restrict__ total,
                                               unsigned* __restrict__ off,
                                               unsigned* __restrict__ cursor) {
    __shared__ unsigned wred[4];
    int b = blockIdx.x, t = threadIdx.x, lane = t & 63, wv = t >> 6;
    int i0 = b * 1024 + t * 4;
    unsigned v[4]; unsigned s = 0;
    #pragma unroll
    for (int j = 0; j < 4; ++j) { int i = i0 + j; v[j] = (i < NN) ? cnt[i] : 0u; s += v[j]; }
    unsigned x = s;
    #pragma unroll
    for (int st = 1; st < 64; st <<= 1) { unsigned u = __shfl_up(x, st, 64); if (lane >= st) x += u; }
    if (lane == 63) wred[wv] = x;
    __syncthreads();
    unsigned woff = 0;
    for (int k = 0; k < 4; ++k) if (k < wv) woff += wred[k];
    unsigned excl = bsum[b] + woff + x - s;
    #pragma unroll
    for (int j = 0; j < 4; ++j) {
        int i = i0 + j;
        if (i < NN) { off[i] = excl; cursor[i] = excl; excl += v[j]; }
    }
    if (b == 0 && t == 0) off[NN] = *total;
}

// CSR fill: interleaved edge meta (src, raw weight) — one 8B store per edge
__global__ void k_fill(const int* __restrict__ ei, const float* __restrict__ ew,
                       unsigned* cursor, uint2* __restrict__ em) {
    int e = blockIdx.x * 256 + threadIdx.x;
    if (e >= EE) return;
    int s = ei[e];
    int d = ei[EE + e];
    unsigned p = atomicAdd(&cursor[d], 1u);
    em[p] = make_uint2((unsigned)s, __float_as_uint(ew[e]));
}

// deg[i] = 1 + sum(raw weights of row i); dinv = rsqrt
__global__ void k_dinv_csr(const unsigned* __restrict__ off,
                           const uint2* __restrict__ em, float* __restrict__ dinv) {
    int i = blockIdx.x * 256 + threadIdx.x;
    if (i >= NN) return;
    unsigned p0 = off[i], p1 = off[i + 1];
    float s = 1.0f;                       // self-loop weight
    for (unsigned p = p0; p < p1; ++p) s += __uint_as_float(em[p].y);
    dinv[i] = (s > 0.f) ? rsqrtf(s) : 0.f;
}

// em[p].w *= dinv[src]*dinv[dst]
__global__ void k_scale(const unsigned* __restrict__ off, const float* __restrict__ dinv,
                        uint2* __restrict__ em) {
    int i = blockIdx.x * 256 + threadIdx.x;
    if (i >= NN) return;
    float di = dinv[i];
    unsigned p0 = off[i], p1 = off[i + 1];
    for (unsigned p = p0; p < p1; ++p) {
        uint2 e = em[p];
        em[p].y = __float_as_uint(dinv[e.x] * __uint_as_float(e.y) * di);
    }
}

// ---------------------------------------------------------------------------
// Weight preconversion: 5 mats W[128][128] f32 -> Wt_hi/lo[col][k] bf16 (W^T)
// ---------------------------------------------------------------------------

__global__ void k_wsplit(const float* W0, const float* W1, const float* W2,
                         const float* W3, const float* W4,
                         unsigned short* __restrict__ wt) {
    int m = blockIdx.x >> 6;
    const float* W = (m == 0) ? W0 : (m == 1) ? W1 : (m == 2) ? W2 : (m == 3) ? W3 : W4;
    int idx = (blockIdx.x & 63) * 256 + threadIdx.x;   // 0..16383
    int k = idx >> 7, j = idx & 127;
    float v = W[idx];
    unsigned short h = f2bf(v);
    unsigned short* hi = wt + (size_t)(2 * m) * C * C;
    unsigned short* lo = wt + (size_t)(2 * m + 1) * C * C;
    hi[j * C + k] = h;
    lo[j * C + k] = f2bf(v - bf2f(h));
}

// x (f32) -> bf16 plane
__global__ void k_tobf(const float* __restrict__ x, unsigned short* __restrict__ xb) {
    int i = (blockIdx.x * 256 + threadIdx.x) * 4;
    if (i >= NN * C) return;
    float4 v = *(const float4*)(x + i);
    union { unsigned short u[4]; uint2 p; } o;
    o.u[0] = f2bf(v.x); o.u[1] = f2bf(v.y); o.u[2] = f2bf(v.z); o.u[3] = f2bf(v.w);
    *(uint2*)(xb + i) = o.p;
}

// ---------------------------------------------------------------------------
// Fused conv layer: out = (Â H) W + b  [+ PReLU]
// Block: 256 thr (4 waves), 64 dst rows. Phase 1: wave gathers 16 rows
// (lane = 2 channels, bf16 source), S accumulated f32, written to swizzled
// LDS as bf16 hi/lo. Phase 2: 3-term bf16 MFMA with W^T frags in VGPRs.
// ---------------------------------------------------------------------------

template<bool PERM>
__global__ __launch_bounds__(256) void k_conv(const unsigned short* __restrict__ H,
                                              const int* __restrict__ perm,
                                              const float* __restrict__ dinv,
                                              const unsigned* __restrict__ off,
                                              const uint2* __restrict__ em,
                                              const unsigned short* __restrict__ Bh,
                                              const unsigned short* __restrict__ Bl,
                                              const float* __restrict__ bias,
                                              const float* __restrict__ prelu,
                                              float* __restrict__ outF,
                                              unsigned short* __restrict__ outB) {
    __shared__ unsigned short Ah[64 * 128];
    __shared__ unsigned short Al[64 * 128];
    int tid  = threadIdx.x;
    int lane = tid & 63;
    int wv   = tid >> 6;
    int row0 = blockIdx.x * 64;

    // B fragments up front (overlaps with gather latency)
    bf16x8 bh[2][4], bl[2][4];
    #pragma unroll
    for (int cf = 0; cf < 2; ++cf) {
        int col = wv * 32 + cf * 16 + (lane & 15);
        #pragma unroll
        for (int kt = 0; kt < 4; ++kt) {
            int k = kt * 32 + (lane >> 4) * 8;
            bh[cf][kt] = *(const bf16x8*)(Bh + (size_t)col * C + k);
            bl[cf][kt] = *(const bf16x8*)(Bl + (size_t)col * C + k);
        }
    }

    const ushort2* H2 = (const ushort2*)H;

    // Phase 1: aggregation. wave wv owns local rows wv*16 .. wv*16+15
    for (int t = 0; t < 16; ++t) {
        int rl = wv * 16 + t;
        int i  = row0 + rl;
        float ax = 0.f, ay = 0.f, cx = 0.f, cy = 0.f;
        if (i < NN) {
            int si = PERM ? perm[i] : i;
            ushort2 hv = H2[(size_t)si * 64 + lane];
            float dv = dinv[i];
            float sn = dv * dv;
            ax = bf2f(hv.x) * sn; ay = bf2f(hv.y) * sn;
            unsigned p = off[i], p1 = off[i + 1];
            for (; p + 4 <= p1; p += 4) {
                uint2 e0 = em[p], e1 = em[p + 1], e2 = em[p + 2], e3 = em[p + 3];
                int s0 = e0.x, s1 = e1.x, s2 = e2.x, s3 = e3.x;
                if (PERM) { s0 = perm[s0]; s1 = perm[s1]; s2 = perm[s2]; s3 = perm[s3]; }
                ushort2 v0 = H2[(size_t)s0 * 64 + lane];
                ushort2 v1 = H2[(size_t)s1 * 64 + lane];
                ushort2 v2 = H2[(size_t)s2 * 64 + lane];
                ushort2 v3 = H2[(size_t)s3 * 64 + lane];
                float w0 = __uint_as_float(e0.y), w1 = __uint_as_float(e1.y);
                float w2 = __uint_as_float(e2.y), w3 = __uint_as_float(e3.y);
                ax += bf2f(v0.x) * w0; ay += bf2f(v0.y) * w0;
                cx += bf2f(v1.x) * w1; cy += bf2f(v1.y) * w1;
                ax += bf2f(v2.x) * w2; ay += bf2f(v2.y) * w2;
                cx += bf2f(v3.x) * w3; cy += bf2f(v3.y) * w3;
            }
            for (; p < p1; ++p) {
                uint2 e0 = em[p];
                int s0 = e0.x; if (PERM) s0 = perm[s0];
                ushort2 v0 = H2[(size_t)s0 * 64 + lane];
                float w0 = __uint_as_float(e0.y);
                ax += bf2f(v0.x) * w0; ay += bf2f(v0.y) * w0;
            }
            ax += cx; ay += cy;
        }
        // S row -> swizzled LDS hi/lo (channels 2*lane, 2*lane+1)
        unsigned short hx = f2bf(ax), hy = f2bf(ay);
        int byte = (rl * 256 + lane * 4) ^ ((rl & 7) << 4);
        ushort2 hh; hh.x = hx; hh.y = hy;
        ushort2 ll; ll.x = f2bf(ax - bf2f(hx)); ll.y = f2bf(ay - bf2f(hy));
        *(ushort2*)((char*)Ah + byte) = hh;
        *(ushort2*)((char*)Al + byte) = ll;
    }

    __syncthreads();

    // Phase 2: MFMA
    f32x4 zero = {0.f, 0.f, 0.f, 0.f};
    f32x4 acc[4][2];
    #pragma unroll
    for (int rf = 0; rf < 4; ++rf)
        #pragma unroll
        for (int cf = 0; cf < 2; ++cf) acc[rf][cf] = zero;

    #pragma unroll
    for (int rf = 0; rf < 4; ++rf) {
        int row = rf * 16 + (lane & 15);
        #pragma unroll
        for (int kt = 0; kt < 4; ++kt) {
            int k = kt * 32 + (lane >> 4) * 8;
            int byte = (row * 256 + k * 2) ^ ((row & 7) << 4);
            bf16x8 ah = *(const bf16x8*)((const char*)Ah + byte);
            bf16x8 al = *(const bf16x8*)((const char*)Al + byte);
            #pragma unroll
            for (int cf = 0; cf < 2; ++cf) {
                acc[rf][cf] = __builtin_amdgcn_mfma_f32_16x16x32_bf16(ah, bh[cf][kt], acc[rf][cf], 0, 0, 0);
                acc[rf][cf] = __builtin_amdgcn_mfma_f32_16x16x32_bf16(al, bh[cf][kt], acc[rf][cf], 0, 0, 0);
                acc[rf][cf] = __builtin_amdgcn_mfma_f32_16x16x32_bf16(ah, bl[cf][kt], acc[rf][cf], 0, 0, 0);
            }
        }
    }

    // Epilogue: + bias, PReLU, store f32 and/or bf16 plane
    #pragma unroll
    for (int cf = 0; cf < 2; ++cf) {
        int col = wv * 32 + cf * 16 + (lane & 15);
        float bv = bias[col];
        float pv = prelu ? prelu[col] : 0.f;
        #pragma unroll
        for (int rf = 0; rf < 4; ++rf) {
            #pragma unroll
            for (int q = 0; q < 4; ++q) {
                int row = row0 + rf * 16 + (lane >> 4) * 4 + q;
                if (row < NN) {
                    float v = acc[rf][cf][q] + bv;
                    if (prelu) v = (v >= 0.f) ? v : pv * v;
                    if (outF) outF[(size_t)row * C + col] = v;
                    if (outB) outB[(size_t)row * C + col] = f2bf(v);
                }
            }
        }
    }
}

// ---------------------------------------------------------------------------
// summary = sigmoid(mean(pos_z, axis=0))
// ---------------------------------------------------------------------------

__global__ __launch_bounds__(256) void k_sum(const float* __restrict__ pos, float* sumbuf) {
    __shared__ float red[256];
    int t = threadIdx.x;
    int c = t & 127;
    int half = t >> 7;
    float acc = 0.f;
    for (int r = blockIdx.x * 2 + half; r < NN; r += gridDim.x * 2)
        acc += pos[(size_t)r * C + c];
    red[t] = acc;
    __syncthreads();
    if (half == 0) atomicAdd(&sumbuf[c], acc + red[t + 128]);
}

__global__ void k_summary(const float* sumbuf, float* out) {
    int t = threadIdx.x;
    if (t < C) {
        float m = sumbuf[t] * (1.0f / (float)NN);
        out[t] = 1.0f / (1.0f + expf(-m));
    }
}

// ---------------------------------------------------------------------------
// q: Student's-t soft assignment. 256 thr: 64 nodes, 4 threads/node.
// ---------------------------------------------------------------------------

__global__ __launch_bounds__(256) void k_q(const float* __restrict__ xo,
                                           const float* __restrict__ mu,
                                           float* __restrict__ qout) {
    __shared__ float sx[64][132];
    __shared__ float smu[KC][128];
    __shared__ float smun[KC];
    int tid = threadIdx.x;
    for (int idx = tid; idx < KC * 128; idx += 256)
        smu[idx >> 7][idx & 127] = mu[idx];
    __syncthreads();
    if (tid < KC) {
        float s = 0.f;
        #pragma unroll 4
        for (int j = 0; j < 128; ++j) { float m = smu[tid][j]; s += m * m; }
        smun[tid] = s;
    }
    int n0 = blockIdx.x * 64;
    for (int idx = tid; idx < 64 * 32; idx += 256) {
        int r = idx >> 5;
        int c = (idx & 31) * 4;
        int gr = n0 + r;
        float4 v = make_float4(0.f, 0.f, 0.f, 0.f);
        if (gr < NN) v = *(const float4*)(xo + (size_t)gr * C + c);
        *(float4*)&sx[r][c] = v;
    }
    __syncthreads();
    int lr = tid >> 2;
    int g  = tid & 3;
    int node = n0 + lr;
    if (node < NN) {
        float ss = 0.f;
        #pragma unroll 8
        for (int j = 0; j < 128; ++j) { float x = sx[lr][j]; ss += x * x; }
        float qv[5]; float qs = 0.f;
        #pragma unroll
        for (int kk = 0; kk < 5; ++kk) {
            int k = g * 5 + kk;
            float dot = 0.f;
            #pragma unroll 8
            for (int j = 0; j < 128; ++j) dot += sx[lr][j] * smu[k][j];
            float d = ss + smun[k] - 2.0f * dot;
            d = fmaxf(d, 0.f);
            float q = 1.0f / (1.0f + d * 5.0f + 1e-8f);
            q = powf(q, 1.2f) * 0.5f;
            qv[kk] = q; qs += q;
        }
        qs += __shfl_xor(qs, 1, 64);
        qs += __shfl_xor(qs, 2, 64);
        float inv = 1.0f / qs;
        #pragma unroll
        for (int kk = 0; kk < 5; ++kk)
            qout[(size_t)node * KC + g * 5 + kk] = qv[kk] * inv;
    }
}

// ---------------------------------------------------------------------------
// launch
// ---------------------------------------------------------------------------

extern "C" void kernel_launch(void* const* d_in, const int* in_sizes, int n_in,
                              void* d_out, int out_size, void* d_ws, size_t ws_size,
                              hipStream_t stream) {
    const float* x    = (const float*)d_in[0];
    const int*   ei   = (const int*)d_in[1];
    const float* ew   = (const float*)d_in[2];
    const int*   perm = (const int*)d_in[3];
    const float* W1 = (const float*)d_in[4];  const float* b1 = (const float*)d_in[5];
    const float* W2 = (const float*)d_in[6];  const float* b2 = (const float*)d_in[7];
    const float* W3 = (const float*)d_in[8];  const float* b3 = (const float*)d_in[9];
    const float* W4 = (const float*)d_in[10]; const float* b4 = (const float*)d_in[11];
    const float* prelu_a = (const float*)d_in[12];
    const float* Wc = (const float*)d_in[13]; const float* bc = (const float*)d_in[14];
    const float* mu = (const float*)d_in[15];

    float* out     = (float*)d_out;
    float* pos_z   = out;                          // [N,128]
    float* neg_z   = out + (size_t)NN * C;         // [N,128]
    float* summary = out + (size_t)2 * NN * C;     // [128]
    float* xout    = summary + C;                  // [N,128]
    float* qout    = xout + (size_t)NN * C;        // [N,20]

    // workspace carve (~46 MB)
    char* w = (char*)d_ws;
    auto carve = [&](size_t bytes) { void* p = (void*)w; w += (bytes + 511) & ~(size_t)511; return p; };
    float*          dinv   = (float*)carve((size_t)NN * 4);
    unsigned*       cnt    = (unsigned*)carve((size_t)(NN + 1) * 4);  // -> off in place
    unsigned*       cursor = (unsigned*)carve((size_t)NN * 4);
    unsigned*       bsum   = (unsigned*)carve(256 * 4);
    unsigned*       total  = (unsigned*)carve(64);
    uint2*          em     = (uint2*)carve((size_t)EE * 8);           // (src, w)
    float*          sumbuf = (float*)carve(512);
    unsigned short* wt     = (unsigned short*)carve((size_t)5 * 2 * C * C * 2);
    unsigned short* B0     = (unsigned short*)carve((size_t)NN * C * 2);
    unsigned short* B1     = (unsigned short*)carve((size_t)NN * C * 2);
    unsigned short* B2     = (unsigned short*)carve((size_t)NN * C * 2);

    unsigned short* Wh[5], *Wl[5];
    for (int m = 0; m < 5; ++m) {
        Wh[m] = wt + (size_t)(2 * m) * C * C;
        Wl[m] = wt + (size_t)(2 * m + 1) * C * C;
    }

    hipMemsetAsync(cnt, 0, (size_t)(NN + 1) * 4, stream);
    hipMemsetAsync(sumbuf, 0, 512, stream);

    int gE = (EE + 255) / 256, gN = (NN + 255) / 256;

    // graph build
    k_hist <<<gE, 256, 0, stream>>>(ei, cnt);
    k_scan1<<<NB, 256, 0, stream>>>(cnt, bsum);
    k_scan2<<<1, 64, 0, stream>>>(bsum, total);
    k_scan3<<<NB, 256, 0, stream>>>(cnt, bsum, total, cnt, cursor);   // cnt := off
    k_fill <<<gE, 256, 0, stream>>>(ei, ew, cursor, em);
    k_dinv_csr<<<gN, 256, 0, stream>>>(cnt, em, dinv);
    k_scale<<<gN, 256, 0, stream>>>(cnt, dinv, em);

    // weight split/transpose + x->bf16
    k_wsplit<<<320, 256, 0, stream>>>(W1, W2, W3, W4, Wc, wt);
    k_tobf  <<<(NN * C / 4 + 255) / 256, 256, 0, stream>>>(x, B0);

    int gC = (NN + 63) / 64;

    // pos chain: B0(x) -> B1 -> B0 -> B1 -> pos_z + B0(shadow)
    k_conv<false><<<gC, 256, 0, stream>>>(B0, nullptr, dinv, cnt, em, Wh[0], Wl[0], b1, nullptr, nullptr, B1);
    // neg layer 1 while B0 still holds x
    k_conv<true> <<<gC, 256, 0, stream>>>(B0, perm,    dinv, cnt, em, Wh[0], Wl[0], b1, nullptr, nullptr, B2);
    k_conv<false><<<gC, 256, 0, stream>>>(B1, nullptr, dinv, cnt, em, Wh[1], Wl[1], b2, nullptr, nullptr, B0);
    k_conv<false><<<gC, 256, 0, stream>>>(B0, nullptr, dinv, cnt, em, Wh[2], Wl[2], b3, nullptr, nullptr, B1);
    k_conv<false><<<gC, 256, 0, stream>>>(B1, nullptr, dinv, cnt, em, Wh[3], Wl[3], b4, prelu_a, pos_z, B0);
    // neg chain: B2 -> B1 -> B2 -> neg_z
    k_conv<false><<<gC, 256, 0, stream>>>(B2, nullptr, dinv, cnt, em, Wh[1], Wl[1], b2, nullptr, nullptr, B1);
    k_conv<false><<<gC, 256, 0, stream>>>(B1, nullptr, dinv, cnt, em, Wh[2], Wl[2], b3, nullptr, nullptr, B2);
    k_conv<false><<<gC, 256, 0, stream>>>(B2, nullptr, dinv, cnt, em, Wh[3], Wl[3], b4, prelu_a, neg_z, nullptr);
    // decoder: B0 (pos_z shadow) -> xout
    k_conv<false><<<gC, 256, 0, stream>>>(B0, nullptr, dinv, cnt, em, Wh[4], Wl[4], bc, nullptr, xout, nullptr);

    // summary
    k_sum<<<256, 256, 0, stream>>>(pos_z, sumbuf);
    k_summary<<<1, 128, 0, stream>>>(sumbuf, summary);

    // q soft assignment
    k_q<<<(NN + 63) / 64, 256, 0, stream>>>(xout, mu, qout);
}

// Round 5
// 772.557 us; speedup vs baseline: 1.9252x; 1.9252x over previous
//
#include <hip/hip_runtime.h>
#include <hip/hip_bf16.h>

// Problem constants (from reference)
constexpr int NN = 50000;   // nodes
constexpr int EE = 800000;  // edges
constexpr int C  = 128;     // channels (IN == H == 128)
constexpr int KC = 20;      // clusters
constexpr int NB = (NN + 1023) / 1024;   // scan blocks (49)

typedef __attribute__((ext_vector_type(8))) short bf16x8;   // 8 bf16 (4 VGPRs)
typedef __attribute__((ext_vector_type(4))) float f32x4;

__device__ inline unsigned short f2bf(float f) {            // RN f32->bf16
    unsigned u = __float_as_uint(f);
    u += 0x7fff + ((u >> 16) & 1);
    return (unsigned short)(u >> 16);
}
__device__ inline float bf2f(unsigned short h) {
    return __uint_as_float(((unsigned)h) << 16);
}

// ---------------------------------------------------------------------------
// Graph preprocessing (int inputs are int32 on device)
// ---------------------------------------------------------------------------

__global__ void k_hist(const int* __restrict__ ei, unsigned* cnt) {
    int e = blockIdx.x * 256 + threadIdx.x;
    if (e >= EE) return;
    atomicAdd(&cnt[ei[EE + e]], 1u);
}

__global__ __launch_bounds__(256) void k_scan1(const unsigned* __restrict__ cnt,
                                               unsigned* __restrict__ bsum) {
    __shared__ unsigned red[256];
    int b = blockIdx.x, t = threadIdx.x;
    int i0 = b * 1024 + t * 4;
    unsigned s = 0;
    #pragma unroll
    for (int j = 0; j < 4; ++j) { int i = i0 + j; s += (i < NN) ? cnt[i] : 0u; }
    red[t] = s; __syncthreads();
    for (int st = 128; st > 0; st >>= 1) { if (t < st) red[t] += red[t + st]; __syncthreads(); }
    if (t == 0) bsum[b] = red[0];
}

__global__ void k_scan2(unsigned* bsum, unsigned* total) {   // 1 block, 64 thr
    int t = threadIdx.x;
    unsigned v = (t < NB) ? bsum[t] : 0u;
    unsigned x = v;
    #pragma unroll
    for (int s = 1; s < 64; s <<= 1) { unsigned u = __shfl_up(x, s, 64); if (t >= s) x += u; }
    if (t < NB) bsum[t] = x - v;     // exclusive block offset
    if (t == 63) *total = x;
}

__global__ __launch_bounds__(256) void k_scan3(const unsigned* __restrict__ cnt,
                                               const unsigned* __restrict__ bsum,
                                               const unsigned* __restrict__ total,
                                               unsigned* __restrict__ off,
                                               unsigned* __restrict__ cursor) {
    __shared__ unsigned wred[4];
    int b = blockIdx.x, t = threadIdx.x, lane = t & 63, wv = t >> 6;
    int i0 = b * 1024 + t * 4;
    unsigned v[4]; unsigned s = 0;
    #pragma unroll
    for (int j = 0; j < 4; ++j) { int i = i0 + j; v[j] = (i < NN) ? cnt[i] : 0u; s += v[j]; }
    unsigned x = s;
    #pragma unroll
    for (int st = 1; st < 64; st <<= 1) { unsigned u = __shfl_up(x, st, 64); if (lane >= st) x += u; }
    if (lane == 63) wred[wv] = x;
    __syncthreads();
    unsigned woff = 0;
    for (int k = 0; k < 4; ++k) if (k < wv) woff += wred[k];
    unsigned excl = bsum[b] + woff + x - s;
    #pragma unroll
    for (int j = 0; j < 4; ++j) {
        int i = i0 + j;
        if (i < NN) { off[i] = excl; cursor[i] = excl; excl += v[j]; }
    }
    if (b == 0 && t == 0) off[NN] = *total;
}

// CSR fill: interleaved edge meta (src, raw weight) — one 8B store per edge
__global__ void k_fill(const int* __restrict__ ei, const float* __restrict__ ew,
                       unsigned* cursor, uint2* __restrict__ em) {
    int e = blockIdx.x * 256 + threadIdx.x;
    if (e >= EE) return;
    int s = ei[e];
    int d = ei[EE + e];
    unsigned p = atomicAdd(&cursor[d], 1u);
    em[p] = make_uint2((unsigned)s, __float_as_uint(ew[e]));
}

// deg[i] = 1 + sum(raw weights of row i); dinv = rsqrt
__global__ void k_dinv_csr(const unsigned* __restrict__ off,
                           const uint2* __restrict__ em, float* __restrict__ dinv) {
    int i = blockIdx.x * 256 + threadIdx.x;
    if (i >= NN) return;
    unsigned p0 = off[i], p1 = off[i + 1];
    float s = 1.0f;                       // self-loop weight
    for (unsigned p = p0; p < p1; ++p) s += __uint_as_float(em[p].y);
    dinv[i] = (s > 0.f) ? rsqrtf(s) : 0.f;
}

// em[p].w *= dinv[src]*dinv[dst]
__global__ void k_scale(const unsigned* __restrict__ off, const float* __restrict__ dinv,
                        uint2* __restrict__ em) {
    int i = blockIdx.x * 256 + threadIdx.x;
    if (i >= NN) return;
    float di = dinv[i];
    unsigned p0 = off[i], p1 = off[i + 1];
    for (unsigned p = p0; p < p1; ++p) {
        uint2 e = em[p];
        em[p].y = __float_as_uint(dinv[e.x] * __uint_as_float(e.y) * di);
    }
}

// ---------------------------------------------------------------------------
// Weight preconversion: 5 mats W[128][128] f32 -> Wt_hi/lo[col][k] bf16 (W^T)
// ---------------------------------------------------------------------------

__global__ void k_wsplit(const float* W0, const float* W1, const float* W2,
                         const float* W3, const float* W4,
                         unsigned short* __restrict__ wt) {
    int m = blockIdx.x >> 6;
    const float* W = (m == 0) ? W0 : (m == 1) ? W1 : (m == 2) ? W2 : (m == 3) ? W3 : W4;
    int idx = (blockIdx.x & 63) * 256 + threadIdx.x;   // 0..16383
    int k = idx >> 7, j = idx & 127;
    float v = W[idx];
    unsigned short h = f2bf(v);
    unsigned short* hi = wt + (size_t)(2 * m) * C * C;
    unsigned short* lo = wt + (size_t)(2 * m + 1) * C * C;
    hi[j * C + k] = h;
    lo[j * C + k] = f2bf(v - bf2f(h));
}

// x (f32) -> bf16 plane
__global__ void k_tobf(const float* __restrict__ x, unsigned short* __restrict__ xb) {
    int i = (blockIdx.x * 256 + threadIdx.x) * 4;
    if (i >= NN * C) return;
    float4 v = *(const float4*)(x + i);
    union { unsigned short u[4]; uint2 p; } o;
    o.u[0] = f2bf(v.x); o.u[1] = f2bf(v.y); o.u[2] = f2bf(v.z); o.u[3] = f2bf(v.w);
    *(uint2*)(xb + i) = o.p;
}

// ---------------------------------------------------------------------------
// Aggregation: S[i] = sum_{e:dst=i} h[src]*w + h[i]*dinv^2   (bf16 h plane)
// One wave per node (max TLP, no barriers); lane = 2 channels.
// Output: S split exactly into hi/lo bf16 planes for the MFMA kernel.
// ---------------------------------------------------------------------------

template<bool PERM>
__global__ __launch_bounds__(256) void k_agg(const unsigned short* __restrict__ H,
                                             const int* __restrict__ perm,
                                             const float* __restrict__ dinv,
                                             const unsigned* __restrict__ off,
                                             const uint2* __restrict__ em,
                                             unsigned short* __restrict__ Sh,
                                             unsigned short* __restrict__ Sl) {
    int i    = (blockIdx.x * 256 + threadIdx.x) >> 6;
    int lane = threadIdx.x & 63;
    if (i >= NN) return;
    const ushort2* H2 = (const ushort2*)H;

    int si = PERM ? perm[i] : i;
    ushort2 hv = H2[(size_t)si * 64 + lane];
    float dv = dinv[i];
    float sn = dv * dv;
    float ax = bf2f(hv.x) * sn, ay = bf2f(hv.y) * sn;
    float cx = 0.f, cy = 0.f;

    unsigned p = off[i], p1 = off[i + 1];
    for (; p + 4 <= p1; p += 4) {
        uint2 e0 = em[p], e1 = em[p + 1], e2 = em[p + 2], e3 = em[p + 3];
        int s0 = e0.x, s1 = e1.x, s2 = e2.x, s3 = e3.x;
        if (PERM) { s0 = perm[s0]; s1 = perm[s1]; s2 = perm[s2]; s3 = perm[s3]; }
        ushort2 v0 = H2[(size_t)s0 * 64 + lane];
        ushort2 v1 = H2[(size_t)s1 * 64 + lane];
        ushort2 v2 = H2[(size_t)s2 * 64 + lane];
        ushort2 v3 = H2[(size_t)s3 * 64 + lane];
        float w0 = __uint_as_float(e0.y), w1 = __uint_as_float(e1.y);
        float w2 = __uint_as_float(e2.y), w3 = __uint_as_float(e3.y);
        ax += bf2f(v0.x) * w0; ay += bf2f(v0.y) * w0;
        cx += bf2f(v1.x) * w1; cy += bf2f(v1.y) * w1;
        ax += bf2f(v2.x) * w2; ay += bf2f(v2.y) * w2;
        cx += bf2f(v3.x) * w3; cy += bf2f(v3.y) * w3;
    }
    for (; p < p1; ++p) {
        uint2 e0 = em[p];
        int s0 = e0.x; if (PERM) s0 = perm[s0];
        ushort2 v0 = H2[(size_t)s0 * 64 + lane];
        float w0 = __uint_as_float(e0.y);
        ax += bf2f(v0.x) * w0; ay += bf2f(v0.y) * w0;
    }
    ax += cx; ay += cy;

    unsigned short hx = f2bf(ax), hy = f2bf(ay);
    ushort2 hh; hh.x = hx; hh.y = hy;
    ushort2 ll; ll.x = f2bf(ax - bf2f(hx)); ll.y = f2bf(ay - bf2f(hy));
    ((ushort2*)Sh)[(size_t)i * 64 + lane] = hh;
    ((ushort2*)Sl)[(size_t)i * 64 + lane] = ll;
}

// ---------------------------------------------------------------------------
// MFMA GEMM: Out[rows,128] = S[rows,128] @ W[128,128], 3-term bf16x2 split.
// Block: 256 thr (4 waves), BM=64 rows, full N=128 (wave = 32-col strip).
// S hi/lo planes staged to XOR-swizzled LDS; W^T frags preloaded to VGPRs.
// Epilogue: +bias (+PReLU), store f32 out and/or bf16 plane.
// ---------------------------------------------------------------------------

__global__ __launch_bounds__(256) void k_mm(const unsigned short* __restrict__ Sh,
                                            const unsigned short* __restrict__ Sl,
                                            const unsigned short* __restrict__ Bh,
                                            const unsigned short* __restrict__ Bl,
                                            const float* __restrict__ bias,
                                            const float* __restrict__ prelu,
                                            float* __restrict__ outF,
                                            unsigned short* __restrict__ outB) {
    __shared__ unsigned short Ah[64 * 128];
    __shared__ unsigned short Al[64 * 128];
    int tid  = threadIdx.x;
    int lane = tid & 63;
    int wv   = tid >> 6;
    int row0 = blockIdx.x * 64;

    // stage S hi/lo -> swizzled LDS (16B per plane per pass)
    {
        int r  = tid >> 2;                 // 0..63
        int c0 = (tid & 3) * 32;
        int gr = row0 + r;
        bool ok = gr < NN;
        const unsigned short* sH = Sh + (size_t)(ok ? gr : 0) * C + c0;
        const unsigned short* sL = Sl + (size_t)(ok ? gr : 0) * C + c0;
        #pragma unroll
        for (int g = 0; g < 4; ++g) {
            uint4 vh = make_uint4(0, 0, 0, 0), vl = make_uint4(0, 0, 0, 0);
            if (ok) {
                vh = *(const uint4*)(sH + g * 8);
                vl = *(const uint4*)(sL + g * 8);
            }
            int k = c0 + g * 8;
            int byte = (r * 256 + k * 2) ^ ((r & 7) << 4);
            *(uint4*)((char*)Ah + byte) = vh;
            *(uint4*)((char*)Al + byte) = vl;
        }
    }

    // B fragments: lane reads Wt[col][k0..k0+8) = W^T, same frag layout as A
    bf16x8 bh[2][4], bl[2][4];
    #pragma unroll
    for (int cf = 0; cf < 2; ++cf) {
        int col = wv * 32 + cf * 16 + (lane & 15);
        #pragma unroll
        for (int kt = 0; kt < 4; ++kt) {
            int k = kt * 32 + (lane >> 4) * 8;
            bh[cf][kt] = *(const bf16x8*)(Bh + (size_t)col * C + k);
            bl[cf][kt] = *(const bf16x8*)(Bl + (size_t)col * C + k);
        }
    }

    __syncthreads();

    f32x4 zero = {0.f, 0.f, 0.f, 0.f};
    f32x4 acc[4][2];
    #pragma unroll
    for (int rf = 0; rf < 4; ++rf)
        #pragma unroll
        for (int cf = 0; cf < 2; ++cf) acc[rf][cf] = zero;

    #pragma unroll
    for (int rf = 0; rf < 4; ++rf) {
        int row = rf * 16 + (lane & 15);
        #pragma unroll
        for (int kt = 0; kt < 4; ++kt) {
            int k = kt * 32 + (lane >> 4) * 8;
            int byte = (row * 256 + k * 2) ^ ((row & 7) << 4);
            bf16x8 ah = *(const bf16x8*)((const char*)Ah + byte);
            bf16x8 al = *(const bf16x8*)((const char*)Al + byte);
            #pragma unroll
            for (int cf = 0; cf < 2; ++cf) {
                acc[rf][cf] = __builtin_amdgcn_mfma_f32_16x16x32_bf16(ah, bh[cf][kt], acc[rf][cf], 0, 0, 0);
                acc[rf][cf] = __builtin_amdgcn_mfma_f32_16x16x32_bf16(al, bh[cf][kt], acc[rf][cf], 0, 0, 0);
                acc[rf][cf] = __builtin_amdgcn_mfma_f32_16x16x32_bf16(ah, bl[cf][kt], acc[rf][cf], 0, 0, 0);
            }
        }
    }

    // Epilogue: C/D layout col=lane&15, row=(lane>>4)*4+q (m89-verified)
    #pragma unroll
    for (int cf = 0; cf < 2; ++cf) {
        int col = wv * 32 + cf * 16 + (lane & 15);
        float bv = bias[col];
        float pv = prelu ? prelu[col] : 0.f;
        #pragma unroll
        for (int rf = 0; rf < 4; ++rf) {
            #pragma unroll
            for (int q = 0; q < 4; ++q) {
                int row = row0 + rf * 16 + (lane >> 4) * 4 + q;
                if (row < NN) {
                    float v = acc[rf][cf][q] + bv;
                    if (prelu) v = (v >= 0.f) ? v : pv * v;
                    if (outF) outF[(size_t)row * C + col] = v;
                    if (outB) outB[(size_t)row * C + col] = f2bf(v);
                }
            }
        }
    }
}

// ---------------------------------------------------------------------------
// summary = sigmoid(mean(pos_z, axis=0))
// ---------------------------------------------------------------------------

__global__ __launch_bounds__(256) void k_sum(const float* __restrict__ pos, float* sumbuf) {
    __shared__ float red[256];
    int t = threadIdx.x;
    int c = t & 127;
    int half = t >> 7;
    float acc = 0.f;
    for (int r = blockIdx.x * 2 + half; r < NN; r += gridDim.x * 2)
        acc += pos[(size_t)r * C + c];
    red[t] = acc;
    __syncthreads();
    if (half == 0) atomicAdd(&sumbuf[c], acc + red[t + 128]);
}

__global__ void k_summary(const float* sumbuf, float* out) {
    int t = threadIdx.x;
    if (t < C) {
        float m = sumbuf[t] * (1.0f / (float)NN);
        out[t] = 1.0f / (1.0f + expf(-m));
    }
}

// ---------------------------------------------------------------------------
// q: Student's-t soft assignment. 256 thr: 64 nodes, 4 threads/node.
// ---------------------------------------------------------------------------

__global__ __launch_bounds__(256) void k_q(const float* __restrict__ xo,
                                           const float* __restrict__ mu,
                                           float* __restrict__ qout) {
    __shared__ float sx[64][132];
    __shared__ float smu[KC][128];
    __shared__ float smun[KC];
    int tid = threadIdx.x;
    for (int idx = tid; idx < KC * 128; idx += 256)
        smu[idx >> 7][idx & 127] = mu[idx];
    __syncthreads();
    if (tid < KC) {
        float s = 0.f;
        #pragma unroll 4
        for (int j = 0; j < 128; ++j) { float m = smu[tid][j]; s += m * m; }
        smun[tid] = s;
    }
    int n0 = blockIdx.x * 64;
    for (int idx = tid; idx < 64 * 32; idx += 256) {
        int r = idx >> 5;
        int c = (idx & 31) * 4;
        int gr = n0 + r;
        float4 v = make_float4(0.f, 0.f, 0.f, 0.f);
        if (gr < NN) v = *(const float4*)(xo + (size_t)gr * C + c);
        *(float4*)&sx[r][c] = v;
    }
    __syncthreads();
    int lr = tid >> 2;
    int g  = tid & 3;
    int node = n0 + lr;
    if (node < NN) {
        float ss = 0.f;
        #pragma unroll 8
        for (int j = 0; j < 128; ++j) { float x = sx[lr][j]; ss += x * x; }
        float qv[5]; float qs = 0.f;
        #pragma unroll
        for (int kk = 0; kk < 5; ++kk) {
            int k = g * 5 + kk;
            float dot = 0.f;
            #pragma unroll 8
            for (int j = 0; j < 128; ++j) dot += sx[lr][j] * smu[k][j];
            float d = ss + smun[k] - 2.0f * dot;
            d = fmaxf(d, 0.f);
            float q = 1.0f / (1.0f + d * 5.0f + 1e-8f);
            q = powf(q, 1.2f) * 0.5f;
            qv[kk] = q; qs += q;
        }
        qs += __shfl_xor(qs, 1, 64);
        qs += __shfl_xor(qs, 2, 64);
        float inv = 1.0f / qs;
        #pragma unroll
        for (int kk = 0; kk < 5; ++kk)
            qout[(size_t)node * KC + g * 5 + kk] = qv[kk] * inv;
    }
}

// ---------------------------------------------------------------------------
// launch
// ---------------------------------------------------------------------------

extern "C" void kernel_launch(void* const* d_in, const int* in_sizes, int n_in,
                              void* d_out, int out_size, void* d_ws, size_t ws_size,
                              hipStream_t stream) {
    const float* x    = (const float*)d_in[0];
    const int*   ei   = (const int*)d_in[1];
    const float* ew   = (const float*)d_in[2];
    const int*   perm = (const int*)d_in[3];
    const float* W1 = (const float*)d_in[4];  const float* b1 = (const float*)d_in[5];
    const float* W2 = (const float*)d_in[6];  const float* b2 = (const float*)d_in[7];
    const float* W3 = (const float*)d_in[8];  const float* b3 = (const float*)d_in[9];
    const float* W4 = (const float*)d_in[10]; const float* b4 = (const float*)d_in[11];
    const float* prelu_a = (const float*)d_in[12];
    const float* Wc = (const float*)d_in[13]; const float* bc = (const float*)d_in[14];
    const float* mu = (const float*)d_in[15];

    float* out     = (float*)d_out;
    float* pos_z   = out;                          // [N,128]
    float* neg_z   = out + (size_t)NN * C;         // [N,128]
    float* summary = out + (size_t)2 * NN * C;     // [128]
    float* xout    = summary + C;                  // [N,128]
    float* qout    = xout + (size_t)NN * C;        // [N,20]

    // workspace carve (~72 MB)
    char* w = (char*)d_ws;
    auto carve = [&](size_t bytes) { void* p = (void*)w; w += (bytes + 511) & ~(size_t)511; return p; };
    float*          dinv   = (float*)carve((size_t)NN * 4);
    unsigned*       cnt    = (unsigned*)carve((size_t)(NN + 1) * 4);  // -> off in place
    unsigned*       cursor = (unsigned*)carve((size_t)NN * 4);
    unsigned*       bsum   = (unsigned*)carve(256 * 4);
    unsigned*       total  = (unsigned*)carve(64);
    uint2*          em     = (uint2*)carve((size_t)EE * 8);           // (src, w)
    float*          sumbuf = (float*)carve(512);
    unsigned short* wt     = (unsigned short*)carve((size_t)5 * 2 * C * C * 2);
    unsigned short* B0     = (unsigned short*)carve((size_t)NN * C * 2);
    unsigned short* B1     = (unsigned short*)carve((size_t)NN * C * 2);
    unsigned short* B2     = (unsigned short*)carve((size_t)NN * C * 2);
    unsigned short* ShP    = (unsigned short*)carve((size_t)NN * C * 2);
    unsigned short* SlP    = (unsigned short*)carve((size_t)NN * C * 2);

    unsigned short* Wh[5], *Wl[5];
    for (int m = 0; m < 5; ++m) {
        Wh[m] = wt + (size_t)(2 * m) * C * C;
        Wl[m] = wt + (size_t)(2 * m + 1) * C * C;
    }

    hipMemsetAsync(cnt, 0, (size_t)(NN + 1) * 4, stream);
    hipMemsetAsync(sumbuf, 0, 512, stream);

    int gE = (EE + 255) / 256, gN = (NN + 255) / 256;

    // graph build
    k_hist <<<gE, 256, 0, stream>>>(ei, cnt);
    k_scan1<<<NB, 256, 0, stream>>>(cnt, bsum);
    k_scan2<<<1, 64, 0, stream>>>(bsum, total);
    k_scan3<<<NB, 256, 0, stream>>>(cnt, bsum, total, cnt, cursor);   // cnt := off
    k_fill <<<gE, 256, 0, stream>>>(ei, ew, cursor, em);
    k_dinv_csr<<<gN, 256, 0, stream>>>(cnt, em, dinv);
    k_scale<<<gN, 256, 0, stream>>>(cnt, dinv, em);

    // weight split/transpose + x->bf16
    k_wsplit<<<320, 256, 0, stream>>>(W1, W2, W3, W4, Wc, wt);
    k_tobf  <<<(NN * C / 4 + 255) / 256, 256, 0, stream>>>(x, B0);

    int gA = (NN + 3) / 4;        // k_agg: one wave per node
    int gM = (NN + 63) / 64;      // k_mm : 64 rows per block

    // layer macro: agg(src plane) -> S ; mm(W) -> dst
    auto layer = [&](const unsigned short* src, const int* prm, int wm,
                     const float* b, const float* pr, float* oF, unsigned short* oB) {
        if (prm)
            k_agg<true><<<gA, 256, 0, stream>>>(src, prm, dinv, cnt, em, ShP, SlP);
        else
            k_agg<false><<<gA, 256, 0, stream>>>(src, nullptr, dinv, cnt, em, ShP, SlP);
        k_mm<<<gM, 256, 0, stream>>>(ShP, SlP, Wh[wm], Wl[wm], b, pr, oF, oB);
    };

    // neg layer 1 first (B0 still holds x), then pos chain
    layer(B0, perm,    0, b1, nullptr, nullptr, B2);   // neg h1 -> B2
    layer(B0, nullptr, 0, b1, nullptr, nullptr, B1);   // pos h1 -> B1
    layer(B1, nullptr, 1, b2, nullptr, nullptr, B0);   // pos h2 -> B0
    layer(B0, nullptr, 2, b3, nullptr, nullptr, B1);   // pos h3 -> B1
    layer(B1, nullptr, 3, b4, prelu_a, pos_z,   B0);   // pos_z (f32 + bf16 shadow B0)
    layer(B2, nullptr, 1, b2, nullptr, nullptr, B1);   // neg h2 -> B1
    layer(B1, nullptr, 2, b3, nullptr, nullptr, B2);   // neg h3 -> B2
    layer(B2, nullptr, 3, b4, prelu_a, neg_z,   nullptr); // neg_z (f32)
    layer(B0, nullptr, 4, bc, nullptr, xout,    nullptr); // decoder -> xout

    // summary
    k_sum<<<256, 256, 0, stream>>>(pos_z, sumbuf);
    k_summary<<<1, 128, 0, stream>>>(sumbuf, summary);

    // q soft assignment
    k_q<<<(NN + 63) / 64, 256, 0, stream>>>(xout, mu, qout);
}

// Round 7
// 675.828 us; speedup vs baseline: 2.2008x; 1.1431x over previous
//
#include <hip/hip_runtime.h>
#include <hip/hip_bf16.h>

// Problem constants (from reference)
constexpr int NN = 50000;   // nodes
constexpr int EE = 800000;  // edges
constexpr int C  = 128;     // channels (IN == H == 128)
constexpr int KC = 20;      // clusters
constexpr int NB = (NN + 1023) / 1024;   // scan blocks (49)

typedef __attribute__((ext_vector_type(8))) short bf16x8;   // 8 bf16 (4 VGPRs)
typedef __attribute__((ext_vector_type(4))) float f32x4;

__device__ inline unsigned short f2bf(float f) {            // RN f32->bf16
    unsigned u = __float_as_uint(f);
    u += 0x7fff + ((u >> 16) & 1);
    return (unsigned short)(u >> 16);
}
__device__ inline float bf2f(unsigned short h) {
    return __uint_as_float(((unsigned)h) << 16);
}

// ---------------------------------------------------------------------------
// Graph preprocessing (int inputs are int32 on device)
// ---------------------------------------------------------------------------

__global__ void k_hist(const int* __restrict__ ei, unsigned* cnt) {
    int e = blockIdx.x * 256 + threadIdx.x;
    if (e >= EE) return;
    atomicAdd(&cnt[ei[EE + e]], 1u);
}

__global__ __launch_bounds__(256) void k_scan1(const unsigned* __restrict__ cnt,
                                               unsigned* __restrict__ bsum) {
    __shared__ unsigned red[256];
    int b = blockIdx.x, t = threadIdx.x;
    int i0 = b * 1024 + t * 4;
    unsigned s = 0;
    #pragma unroll
    for (int j = 0; j < 4; ++j) { int i = i0 + j; s += (i < NN) ? cnt[i] : 0u; }
    red[t] = s; __syncthreads();
    for (int st = 128; st > 0; st >>= 1) { if (t < st) red[t] += red[t + st]; __syncthreads(); }
    if (t == 0) bsum[b] = red[0];
}

__global__ void k_scan2(unsigned* bsum, unsigned* total) {   // 1 block, 64 thr
    int t = threadIdx.x;
    unsigned v = (t < NB) ? bsum[t] : 0u;
    unsigned x = v;
    #pragma unroll
    for (int s = 1; s < 64; s <<= 1) { unsigned u = __shfl_up(x, s, 64); if (t >= s) x += u; }
    if (t < NB) bsum[t] = x - v;     // exclusive block offset
    if (t == 63) *total = x;
}

__global__ __launch_bounds__(256) void k_scan3(const unsigned* __restrict__ cnt,
                                               const unsigned* __restrict__ bsum,
                                               const unsigned* __restrict__ total,
                                               unsigned* __restrict__ off,
                                               unsigned* __restrict__ cursor) {
    __shared__ unsigned wred[4];
    int b = blockIdx.x, t = threadIdx.x, lane = t & 63, wv = t >> 6;
    int i0 = b * 1024 + t * 4;
    unsigned v[4]; unsigned s = 0;
    #pragma unroll
    for (int j = 0; j < 4; ++j) { int i = i0 + j; v[j] = (i < NN) ? cnt[i] : 0u; s += v[j]; }
    unsigned x = s;
    #pragma unroll
    for (int st = 1; st < 64; st <<= 1) { unsigned u = __shfl_up(x, st, 64); if (lane >= st) x += u; }
    if (lane == 63) wred[wv] = x;
    __syncthreads();
    unsigned woff = 0;
    for (int k = 0; k < 4; ++k) if (k < wv) woff += wred[k];
    unsigned excl = bsum[b] + woff + x - s;
    #pragma unroll
    for (int j = 0; j < 4; ++j) {
        int i = i0 + j;
        if (i < NN) { off[i] = excl; cursor[i] = excl; excl += v[j]; }
    }
    if (b == 0 && t == 0) off[NN] = *total;
}

// CSR fill: interleaved edge meta (src, raw weight) — one 8B store per edge
__global__ void k_fill(const int* __restrict__ ei, const float* __restrict__ ew,
                       unsigned* cursor, uint2* __restrict__ em) {
    int e = blockIdx.x * 256 + threadIdx.x;
    if (e >= EE) return;
    int s = ei[e];
    int d = ei[EE + e];
    unsigned p = atomicAdd(&cursor[d], 1u);
    em[p] = make_uint2((unsigned)s, __float_as_uint(ew[e]));
}

// deg[i] = 1 + sum(raw weights of row i); dinv = rsqrt
__global__ void k_dinv_csr(const unsigned* __restrict__ off,
                           const uint2* __restrict__ em, float* __restrict__ dinv) {
    int i = blockIdx.x * 256 + threadIdx.x;
    if (i >= NN) return;
    unsigned p0 = off[i], p1 = off[i + 1];
    float s = 1.0f;                       // self-loop weight
    for (unsigned p = p0; p < p1; ++p) s += __uint_as_float(em[p].y);
    dinv[i] = (s > 0.f) ? rsqrtf(s) : 0.f;
}

// em[p].w *= dinv[src]*dinv[dst]
__global__ void k_scale(const unsigned* __restrict__ off, const float* __restrict__ dinv,
                        uint2* __restrict__ em) {
    int i = blockIdx.x * 256 + threadIdx.x;
    if (i >= NN) return;
    float di = dinv[i];
    unsigned p0 = off[i], p1 = off[i + 1];
    for (unsigned p = p0; p < p1; ++p) {
        uint2 e = em[p];
        em[p].y = __float_as_uint(dinv[e.x] * __uint_as_float(e.y) * di);
    }
}

// ---------------------------------------------------------------------------
// Weight preconversion: 5 mats W[128][128] f32 -> Wt_hi/lo[col][k] bf16 (W^T)
// ---------------------------------------------------------------------------

__global__ void k_wsplit(const float* W0, const float* W1, const float* W2,
                         const float* W3, const float* W4,
                         unsigned short* __restrict__ wt) {
    int m = blockIdx.x >> 6;
    const float* W = (m == 0) ? W0 : (m == 1) ? W1 : (m == 2) ? W2 : (m == 3) ? W3 : W4;
    int idx = (blockIdx.x & 63) * 256 + threadIdx.x;   // 0..16383
    int k = idx >> 7, j = idx & 127;
    float v = W[idx];
    unsigned short h = f2bf(v);
    unsigned short* hi = wt + (size_t)(2 * m) * C * C;
    unsigned short* lo = wt + (size_t)(2 * m + 1) * C * C;
    hi[j * C + k] = h;
    lo[j * C + k] = f2bf(v - bf2f(h));
}

// x (f32) -> bf16 plane
__global__ void k_tobf(const float* __restrict__ x, unsigned short* __restrict__ xb) {
    int i = (blockIdx.x * 256 + threadIdx.x) * 4;
    if (i >= NN * C) return;
    float4 v = *(const float4*)(x + i);
    union { unsigned short u[4]; uint2 p; } o;
    o.u[0] = f2bf(v.x); o.u[1] = f2bf(v.y); o.u[2] = f2bf(v.z); o.u[3] = f2bf(v.w);
    *(uint2*)(xb + i) = o.p;
}

// ---------------------------------------------------------------------------
// Aggregation v4: S[i] = sum_{e:dst=i} h[src]*w + h[i]*dinv^2  (bf16 h plane)
// One wave per node. Edge metas staged once per 64-edge batch via a single
// coalesced load into wave-private LDS (no shfl, no cross-wave sync). Lane
// groups (16 lanes, g=lane>>4) gather FULL 256B rows (uint4 = 8ch/lane) for
// edges t = g, g+4, ... -> 4 independent gather chains per wave.
// Cross-group butterfly reduce; group 0 writes Sh, group 1 writes Sl.
// ---------------------------------------------------------------------------

template<bool PERM>
__global__ __launch_bounds__(256) void k_agg(const unsigned short* __restrict__ H,
                                             const int* __restrict__ perm,
                                             const float* __restrict__ dinv,
                                             const unsigned* __restrict__ off,
                                             const uint2* __restrict__ em,
                                             unsigned short* __restrict__ Sh,
                                             unsigned short* __restrict__ Sl) {
    __shared__ uint2 sem[4][64];          // per-wave edge staging (2KB)
    int tid  = threadIdx.x;
    int i    = (blockIdx.x * 256 + tid) >> 6;
    int lane = tid & 63;
    int wid  = tid >> 6;
    if (i >= NN) return;
    int g  = lane >> 4;        // group 0..3
    int il = lane & 15;        // lane within group -> channels il*8 .. il*8+7
    const uint4* H4 = (const uint4*)H;   // row = 16 uint4 = 256B

    float a[8];
    // self term (group 0 scales by dinv^2, others contribute 0)
    {
        int si = PERM ? perm[i] : i;
        uint4 hv = H4[(size_t)si * 16 + il];
        float dv = dinv[i];
        float sn = (g == 0) ? dv * dv : 0.f;
        a[0] = __uint_as_float(hv.x << 16) * sn;
        a[1] = __uint_as_float(hv.x & 0xffff0000u) * sn;
        a[2] = __uint_as_float(hv.y << 16) * sn;
        a[3] = __uint_as_float(hv.y & 0xffff0000u) * sn;
        a[4] = __uint_as_float(hv.z << 16) * sn;
        a[5] = __uint_as_float(hv.z & 0xffff0000u) * sn;
        a[6] = __uint_as_float(hv.w << 16) * sn;
        a[7] = __uint_as_float(hv.w & 0xffff0000u) * sn;
    }

    unsigned p0 = off[i], p1 = off[i + 1];
    for (unsigned base = p0; base < p1; base += 64) {
        unsigned rem = p1 - base;
        int cap = rem < 64u ? (int)rem : 64;
        // one coalesced 8B/lane load -> wave-private LDS (same-wave ordering,
        // no barrier needed; compiler orders may-aliasing ds ops)
        sem[wid][lane] = em[base + ((unsigned)lane < rem ? (unsigned)lane : 0u)];
        #pragma unroll 4
        for (int t = g; t < cap; t += 4) {
            uint2 e = sem[wid][t];         // group-uniform LDS broadcast
            unsigned sv = e.x;
            if (PERM) sv = (unsigned)perm[sv];
            float wv = __uint_as_float(e.y);
            uint4 hv = H4[(size_t)sv * 16 + il];
            a[0] += __uint_as_float(hv.x << 16) * wv;
            a[1] += __uint_as_float(hv.x & 0xffff0000u) * wv;
            a[2] += __uint_as_float(hv.y << 16) * wv;
            a[3] += __uint_as_float(hv.y & 0xffff0000u) * wv;
            a[4] += __uint_as_float(hv.z << 16) * wv;
            a[5] += __uint_as_float(hv.z & 0xffff0000u) * wv;
            a[6] += __uint_as_float(hv.w << 16) * wv;
            a[7] += __uint_as_float(hv.w & 0xffff0000u) * wv;
        }
    }

    // cross-group butterfly (lanes il, il+16, il+32, il+48 hold partials)
    #pragma unroll
    for (int j = 0; j < 8; ++j) {
        a[j] += __shfl_xor(a[j], 16, 64);
        a[j] += __shfl_xor(a[j], 32, 64);
    }

    // pack + write: group 0 -> Sh, group 1 -> Sl (a[] bit-identical across groups)
    if (g < 2) {
        unsigned short h[8], l[8];
        #pragma unroll
        for (int j = 0; j < 8; ++j) {
            h[j] = f2bf(a[j]);
            l[j] = f2bf(a[j] - bf2f(h[j]));
        }
        uint4 o;
        const unsigned short* src = (g == 0) ? h : l;
        o.x = (unsigned)src[0] | ((unsigned)src[1] << 16);
        o.y = (unsigned)src[2] | ((unsigned)src[3] << 16);
        o.z = (unsigned)src[4] | ((unsigned)src[5] << 16);
        o.w = (unsigned)src[6] | ((unsigned)src[7] << 16);
        unsigned short* dst = (g == 0) ? Sh : Sl;
        ((uint4*)dst)[(size_t)i * 16 + il] = o;
    }
}

// ---------------------------------------------------------------------------
// MFMA GEMM: Out[rows,128] = S[rows,128] @ W[128,128], 3-term bf16x2 split.
// Block: 256 thr (4 waves), BM=64 rows, full N=128 (wave = 32-col strip).
// S hi/lo planes staged to XOR-swizzled LDS; W^T frags preloaded to VGPRs.
// Epilogue: +bias (+PReLU), store f32 out and/or bf16 plane.
// ---------------------------------------------------------------------------

__global__ __launch_bounds__(256) void k_mm(const unsigned short* __restrict__ Sh,
                                            const unsigned short* __restrict__ Sl,
                                            const unsigned short* __restrict__ Bh,
                                            const unsigned short* __restrict__ Bl,
                                            const float* __restrict__ bias,
                                            const float* __restrict__ prelu,
                                            float* __restrict__ outF,
                                            unsigned short* __restrict__ outB) {
    __shared__ unsigned short Ah[64 * 128];
    __shared__ unsigned short Al[64 * 128];
    int tid  = threadIdx.x;
    int lane = tid & 63;
    int wv   = tid >> 6;
    int row0 = blockIdx.x * 64;

    // stage S hi/lo -> swizzled LDS (16B per plane per pass)
    {
        int r  = tid >> 2;                 // 0..63
        int c0 = (tid & 3) * 32;
        int gr = row0 + r;
        bool ok = gr < NN;
        const unsigned short* sH = Sh + (size_t)(ok ? gr : 0) * C + c0;
        const unsigned short* sL = Sl + (size_t)(ok ? gr : 0) * C + c0;
        #pragma unroll
        for (int g = 0; g < 4; ++g) {
            uint4 vh = make_uint4(0, 0, 0, 0), vl = make_uint4(0, 0, 0, 0);
            if (ok) {
                vh = *(const uint4*)(sH + g * 8);
                vl = *(const uint4*)(sL + g * 8);
            }
            int k = c0 + g * 8;
            int byte = (r * 256 + k * 2) ^ ((r & 7) << 4);
            *(uint4*)((char*)Ah + byte) = vh;
            *(uint4*)((char*)Al + byte) = vl;
        }
    }

    // B fragments: lane reads Wt[col][k0..k0+8) = W^T, same frag layout as A
    bf16x8 bh[2][4], bl[2][4];
    #pragma unroll
    for (int cf = 0; cf < 2; ++cf) {
        int col = wv * 32 + cf * 16 + (lane & 15);
        #pragma unroll
        for (int kt = 0; kt < 4; ++kt) {
            int k = kt * 32 + (lane >> 4) * 8;
            bh[cf][kt] = *(const bf16x8*)(Bh + (size_t)col * C + k);
            bl[cf][kt] = *(const bf16x8*)(Bl + (size_t)col * C + k);
        }
    }

    __syncthreads();

    f32x4 zero = {0.f, 0.f, 0.f, 0.f};
    f32x4 acc[4][2];
    #pragma unroll
    for (int rf = 0; rf < 4; ++rf)
        #pragma unroll
        for (int cf = 0; cf < 2; ++cf) acc[rf][cf] = zero;

    #pragma unroll
    for (int rf = 0; rf < 4; ++rf) {
        int row = rf * 16 + (lane & 15);
        #pragma unroll
        for (int kt = 0; kt < 4; ++kt) {
            int k = kt * 32 + (lane >> 4) * 8;
            int byte = (row * 256 + k * 2) ^ ((row & 7) << 4);
            bf16x8 ah = *(const bf16x8*)((const char*)Ah + byte);
            bf16x8 al = *(const bf16x8*)((const char*)Al + byte);
            #pragma unroll
            for (int cf = 0; cf < 2; ++cf) {
                acc[rf][cf] = __builtin_amdgcn_mfma_f32_16x16x32_bf16(ah, bh[cf][kt], acc[rf][cf], 0, 0, 0);
                acc[rf][cf] = __builtin_amdgcn_mfma_f32_16x16x32_bf16(al, bh[cf][kt], acc[rf][cf], 0, 0, 0);
                acc[rf][cf] = __builtin_amdgcn_mfma_f32_16x16x32_bf16(ah, bl[cf][kt], acc[rf][cf], 0, 0, 0);
            }
        }
    }

    // Epilogue: C/D layout col=lane&15, row=(lane>>4)*4+q (m89-verified)
    #pragma unroll
    for (int cf = 0; cf < 2; ++cf) {
        int col = wv * 32 + cf * 16 + (lane & 15);
        float bv = bias[col];
        float pv = prelu ? prelu[col] : 0.f;
        #pragma unroll
        for (int rf = 0; rf < 4; ++rf) {
            #pragma unroll
            for (int q = 0; q < 4; ++q) {
                int row = row0 + rf * 16 + (lane >> 4) * 4 + q;
                if (row < NN) {
                    float v = acc[rf][cf][q] + bv;
                    if (prelu) v = (v >= 0.f) ? v : pv * v;
                    if (outF) outF[(size_t)row * C + col] = v;
                    if (outB) outB[(size_t)row * C + col] = f2bf(v);
                }
            }
        }
    }
}

// ---------------------------------------------------------------------------
// summary = sigmoid(mean(pos_z, axis=0))
// ---------------------------------------------------------------------------

__global__ __launch_bounds__(256) void k_sum(const float* __restrict__ pos, float* sumbuf) {
    __shared__ float red[256];
    int t = threadIdx.x;
    int c = t & 127;
    int half = t >> 7;
    float acc = 0.f;
    for (int r = blockIdx.x * 2 + half; r < NN; r += gridDim.x * 2)
        acc += pos[(size_t)r * C + c];
    red[t] = acc;
    __syncthreads();
    if (half == 0) atomicAdd(&sumbuf[c], acc + red[t + 128]);
}

__global__ void k_summary(const float* sumbuf, float* out) {
    int t = threadIdx.x;
    if (t < C) {
        float m = sumbuf[t] * (1.0f / (float)NN);
        out[t] = 1.0f / (1.0f + expf(-m));
    }
}

// ---------------------------------------------------------------------------
// q: Student's-t soft assignment. 256 thr: 64 nodes, 4 threads/node.
// ---------------------------------------------------------------------------

__global__ __launch_bounds__(256) void k_q(const float* __restrict__ xo,
                                           const float* __restrict__ mu,
                                           float* __restrict__ qout) {
    __shared__ float sx[64][132];
    __shared__ float smu[KC][128];
    __shared__ float smun[KC];
    int tid = threadIdx.x;
    for (int idx = tid; idx < KC * 128; idx += 256)
        smu[idx >> 7][idx & 127] = mu[idx];
    __syncthreads();
    if (tid < KC) {
        float s = 0.f;
        #pragma unroll 4
        for (int j = 0; j < 128; ++j) { float m = smu[tid][j]; s += m * m; }
        smun[tid] = s;
    }
    int n0 = blockIdx.x * 64;
    for (int idx = tid; idx < 64 * 32; idx += 256) {
        int r = idx >> 5;
        int c = (idx & 31) * 4;
        int gr = n0 + r;
        float4 v = make_float4(0.f, 0.f, 0.f, 0.f);
        if (gr < NN) v = *(const float4*)(xo + (size_t)gr * C + c);
        *(float4*)&sx[r][c] = v;
    }
    __syncthreads();
    int lr = tid >> 2;
    int g  = tid & 3;
    int node = n0 + lr;
    if (node < NN) {
        float ss = 0.f;
        #pragma unroll 8
        for (int j = 0; j < 128; ++j) { float x = sx[lr][j]; ss += x * x; }
        float qv[5]; float qs = 0.f;
        #pragma unroll
        for (int kk = 0; kk < 5; ++kk) {
            int k = g * 5 + kk;
            float dot = 0.f;
            #pragma unroll 8
            for (int j = 0; j < 128; ++j) dot += sx[lr][j] * smu[k][j];
            float d = ss + smun[k] - 2.0f * dot;
            d = fmaxf(d, 0.f);
            float q = 1.0f / (1.0f + d * 5.0f + 1e-8f);
            q = powf(q, 1.2f) * 0.5f;
            qv[kk] = q; qs += q;
        }
        qs += __shfl_xor(qs, 1, 64);
        qs += __shfl_xor(qs, 2, 64);
        float inv = 1.0f / qs;
        #pragma unroll
        for (int kk = 0; kk < 5; ++kk)
            qout[(size_t)node * KC + g * 5 + kk] = qv[kk] * inv;
    }
}

// ---------------------------------------------------------------------------
// launch
// ---------------------------------------------------------------------------

extern "C" void kernel_launch(void* const* d_in, const int* in_sizes, int n_in,
                              void* d_out, int out_size, void* d_ws, size_t ws_size,
                              hipStream_t stream) {
    const float* x    = (const float*)d_in[0];
    const int*   ei   = (const int*)d_in[1];
    const float* ew   = (const float*)d_in[2];
    const int*   perm = (const int*)d_in[3];
    const float* W1 = (const float*)d_in[4];  const float* b1 = (const float*)d_in[5];
    const float* W2 = (const float*)d_in[6];  const float* b2 = (const float*)d_in[7];
    const float* W3 = (const float*)d_in[8];  const float* b3 = (const float*)d_in[9];
    const float* W4 = (const float*)d_in[10]; const float* b4 = (const float*)d_in[11];
    const float* prelu_a = (const float*)d_in[12];
    const float* Wc = (const float*)d_in[13]; const float* bc = (const float*)d_in[14];
    const float* mu = (const float*)d_in[15];

    float* out     = (float*)d_out;
    float* pos_z   = out;                          // [N,128]
    float* neg_z   = out + (size_t)NN * C;         // [N,128]
    float* summary = out + (size_t)2 * NN * C;     // [128]
    float* xout    = summary + C;                  // [N,128]
    float* qout    = xout + (size_t)NN * C;        // [N,20]

    // workspace carve (~72 MB)
    char* w = (char*)d_ws;
    auto carve = [&](size_t bytes) { void* p = (void*)w; w += (bytes + 511) & ~(size_t)511; return p; };
    float*          dinv   = (float*)carve((size_t)NN * 4);
    unsigned*       cnt    = (unsigned*)carve((size_t)(NN + 1) * 4);  // -> off in place
    unsigned*       cursor = (unsigned*)carve((size_t)NN * 4);
    unsigned*       bsum   = (unsigned*)carve(256 * 4);
    unsigned*       total  = (unsigned*)carve(64);
    uint2*          em     = (uint2*)carve((size_t)EE * 8);           // (src, w)
    float*          sumbuf = (float*)carve(512);
    unsigned short* wt     = (unsigned short*)carve((size_t)5 * 2 * C * C * 2);
    unsigned short* B0     = (unsigned short*)carve((size_t)NN * C * 2);
    unsigned short* B1     = (unsigned short*)carve((size_t)NN * C * 2);
    unsigned short* B2     = (unsigned short*)carve((size_t)NN * C * 2);
    unsigned short* ShP    = (unsigned short*)carve((size_t)NN * C * 2);
    unsigned short* SlP    = (unsigned short*)carve((size_t)NN * C * 2);

    unsigned short* Wh[5], *Wl[5];
    for (int m = 0; m < 5; ++m) {
        Wh[m] = wt + (size_t)(2 * m) * C * C;
        Wl[m] = wt + (size_t)(2 * m + 1) * C * C;
    }

    hipMemsetAsync(cnt, 0, (size_t)(NN + 1) * 4, stream);
    hipMemsetAsync(sumbuf, 0, 512, stream);

    int gE = (EE + 255) / 256, gN = (NN + 255) / 256;

    // graph build
    k_hist <<<gE, 256, 0, stream>>>(ei, cnt);
    k_scan1<<<NB, 256, 0, stream>>>(cnt, bsum);
    k_scan2<<<1, 64, 0, stream>>>(bsum, total);
    k_scan3<<<NB, 256, 0, stream>>>(cnt, bsum, total, cnt, cursor);   // cnt := off
    k_fill <<<gE, 256, 0, stream>>>(ei, ew, cursor, em);
    k_dinv_csr<<<gN, 256, 0, stream>>>(cnt, em, dinv);
    k_scale<<<gN, 256, 0, stream>>>(cnt, dinv, em);

    // weight split/transpose + x->bf16
    k_wsplit<<<320, 256, 0, stream>>>(W1, W2, W3, W4, Wc, wt);
    k_tobf  <<<(NN * C / 4 + 255) / 256, 256, 0, stream>>>(x, B0);

    int gA = (NN + 3) / 4;        // k_agg: one wave per node
    int gM = (NN + 63) / 64;      // k_mm : 64 rows per block

    // layer macro: agg(src plane) -> S ; mm(W) -> dst
    auto layer = [&](const unsigned short* src, const int* prm, int wm,
                     const float* b, const float* pr, float* oF, unsigned short* oB) {
        if (prm)
            k_agg<true><<<gA, 256, 0, stream>>>(src, prm, dinv, cnt, em, ShP, SlP);
        else
            k_agg<false><<<gA, 256, 0, stream>>>(src, nullptr, dinv, cnt, em, ShP, SlP);
        k_mm<<<gM, 256, 0, stream>>>(ShP, SlP, Wh[wm], Wl[wm], b, pr, oF, oB);
    };

    // neg layer 1 first (B0 still holds x), then pos chain
    layer(B0, perm,    0, b1, nullptr, nullptr, B2);   // neg h1 -> B2
    layer(B0, nullptr, 0, b1, nullptr, nullptr, B1);   // pos h1 -> B1
    layer(B1, nullptr, 1, b2, nullptr, nullptr, B0);   // pos h2 -> B0
    layer(B0, nullptr, 2, b3, nullptr, nullptr, B1);   // pos h3 -> B1
    layer(B1, nullptr, 3, b4, prelu_a, pos_z,   B0);   // pos_z (f32 + bf16 shadow B0)
    layer(B2, nullptr, 1, b2, nullptr, nullptr, B1);   // neg h2 -> B1
    layer(B1, nullptr, 2, b3, nullptr, nullptr, B2);   // neg h3 -> B2
    layer(B2, nullptr, 3, b4, prelu_a, neg_z,   nullptr); // neg_z (f32)
    layer(B0, nullptr, 4, bc, nullptr, xout,    nullptr); // decoder -> xout

    // summary
    k_sum<<<256, 256, 0, stream>>>(pos_z, sumbuf);
    k_summary<<<1, 128, 0, stream>>>(sumbuf, summary);

    // q soft assignment
    k_q<<<(NN + 63) / 64, 256, 0, stream>>>(xout, mu, qout);
}

// Round 8
// 600.435 us; speedup vs baseline: 2.4771x; 1.1256x over previous
//
#include <hip/hip_runtime.h>
#include <hip/hip_bf16.h>

// Problem constants (from reference)
constexpr int NN = 50000;   // nodes
constexpr int EE = 800000;  // edges
constexpr int C  = 128;     // channels (IN == H == 128)
constexpr int KC = 20;      // clusters
constexpr int NB = (NN + 1023) / 1024;   // scan blocks (49)

typedef __attribute__((ext_vector_type(8))) short bf16x8;   // 8 bf16 (4 VGPRs)
typedef __attribute__((ext_vector_type(4))) float f32x4;

__device__ inline unsigned short f2bf(float f) {            // RN f32->bf16
    unsigned u = __float_as_uint(f);
    u += 0x7fff + ((u >> 16) & 1);
    return (unsigned short)(u >> 16);
}
__device__ inline float bf2f(unsigned short h) {
    return __uint_as_float(((unsigned)h) << 16);
}

// ---------------------------------------------------------------------------
// Graph preprocessing (int inputs are int32 on device)
// ---------------------------------------------------------------------------

__global__ void k_hist(const int* __restrict__ ei, unsigned* cnt) {
    int e = blockIdx.x * 256 + threadIdx.x;
    if (e >= EE) return;
    atomicAdd(&cnt[ei[EE + e]], 1u);
}

__global__ __launch_bounds__(256) void k_scan1(const unsigned* __restrict__ cnt,
                                               unsigned* __restrict__ bsum) {
    __shared__ unsigned red[256];
    int b = blockIdx.x, t = threadIdx.x;
    int i0 = b * 1024 + t * 4;
    unsigned s = 0;
    #pragma unroll
    for (int j = 0; j < 4; ++j) { int i = i0 + j; s += (i < NN) ? cnt[i] : 0u; }
    red[t] = s; __syncthreads();
    for (int st = 128; st > 0; st >>= 1) { if (t < st) red[t] += red[t + st]; __syncthreads(); }
    if (t == 0) bsum[b] = red[0];
}

__global__ void k_scan2(unsigned* bsum, unsigned* total) {   // 1 block, 64 thr
    int t = threadIdx.x;
    unsigned v = (t < NB) ? bsum[t] : 0u;
    unsigned x = v;
    #pragma unroll
    for (int s = 1; s < 64; s <<= 1) { unsigned u = __shfl_up(x, s, 64); if (t >= s) x += u; }
    if (t < NB) bsum[t] = x - v;     // exclusive block offset
    if (t == 63) *total = x;
}

__global__ __launch_bounds__(256) void k_scan3(const unsigned* __restrict__ cnt,
                                               const unsigned* __restrict__ bsum,
                                               const unsigned* __restrict__ total,
                                               unsigned* __restrict__ off,
                                               unsigned* __restrict__ cursor) {
    __shared__ unsigned wred[4];
    int b = blockIdx.x, t = threadIdx.x, lane = t & 63, wv = t >> 6;
    int i0 = b * 1024 + t * 4;
    unsigned v[4]; unsigned s = 0;
    #pragma unroll
    for (int j = 0; j < 4; ++j) { int i = i0 + j; v[j] = (i < NN) ? cnt[i] : 0u; s += v[j]; }
    unsigned x = s;
    #pragma unroll
    for (int st = 1; st < 64; st <<= 1) { unsigned u = __shfl_up(x, st, 64); if (lane >= st) x += u; }
    if (lane == 63) wred[wv] = x;
    __syncthreads();
    unsigned woff = 0;
    for (int k = 0; k < 4; ++k) if (k < wv) woff += wred[k];
    unsigned excl = bsum[b] + woff + x - s;
    #pragma unroll
    for (int j = 0; j < 4; ++j) {
        int i = i0 + j;
        if (i < NN) { off[i] = excl; cursor[i] = excl; excl += v[j]; }
    }
    if (b == 0 && t == 0) off[NN] = *total;
}

// CSR fill: interleaved edge meta (src, raw weight) — one 8B store per edge
__global__ void k_fill(const int* __restrict__ ei, const float* __restrict__ ew,
                       unsigned* cursor, uint2* __restrict__ em) {
    int e = blockIdx.x * 256 + threadIdx.x;
    if (e >= EE) return;
    int s = ei[e];
    int d = ei[EE + e];
    unsigned p = atomicAdd(&cursor[d], 1u);
    em[p] = make_uint2((unsigned)s, __float_as_uint(ew[e]));
}

// deg[i] = 1 + sum(raw weights of row i); dinv = rsqrt
__global__ void k_dinv_csr(const unsigned* __restrict__ off,
                           const uint2* __restrict__ em, float* __restrict__ dinv) {
    int i = blockIdx.x * 256 + threadIdx.x;
    if (i >= NN) return;
    unsigned p0 = off[i], p1 = off[i + 1];
    float s = 1.0f;                       // self-loop weight
    for (unsigned p = p0; p < p1; ++p) s += __uint_as_float(em[p].y);
    dinv[i] = (s > 0.f) ? rsqrtf(s) : 0.f;
}

// em[p].w *= dinv[src]*dinv[dst]
__global__ void k_scale(const unsigned* __restrict__ off, const float* __restrict__ dinv,
                        uint2* __restrict__ em) {
    int i = blockIdx.x * 256 + threadIdx.x;
    if (i >= NN) return;
    float di = dinv[i];
    unsigned p0 = off[i], p1 = off[i + 1];
    for (unsigned p = p0; p < p1; ++p) {
        uint2 e = em[p];
        em[p].y = __float_as_uint(dinv[e.x] * __uint_as_float(e.y) * di);
    }
}

// ---------------------------------------------------------------------------
// Weight preconversion: 5 mats W[128][128] f32 -> Wt_hi/lo[col][k] bf16 (W^T)
// ---------------------------------------------------------------------------

__global__ void k_wsplit(const float* W0, const float* W1, const float* W2,
                         const float* W3, const float* W4,
                         unsigned short* __restrict__ wt) {
    int m = blockIdx.x >> 6;
    const float* W = (m == 0) ? W0 : (m == 1) ? W1 : (m == 2) ? W2 : (m == 3) ? W3 : W4;
    int idx = (blockIdx.x & 63) * 256 + threadIdx.x;   // 0..16383
    int k = idx >> 7, j = idx & 127;
    float v = W[idx];
    unsigned short h = f2bf(v);
    unsigned short* hi = wt + (size_t)(2 * m) * C * C;
    unsigned short* lo = wt + (size_t)(2 * m + 1) * C * C;
    hi[j * C + k] = h;
    lo[j * C + k] = f2bf(v - bf2f(h));
}

// ---------------------------------------------------------------------------
// k_mm_f32: G = x @ W (x f32, 3-term hi/lo split) -> bf16 plane. Layer-1 only.
// ---------------------------------------------------------------------------

__global__ __launch_bounds__(256) void k_mm_f32(const float* __restrict__ A,
                                                const unsigned short* __restrict__ Bh,
                                                const unsigned short* __restrict__ Bl,
                                                unsigned short* __restrict__ G) {
    __shared__ unsigned short Ah[64 * 128];
    __shared__ unsigned short Al[64 * 128];
    int tid  = threadIdx.x;
    int lane = tid & 63;
    int wv   = tid >> 6;
    int row0 = blockIdx.x * 64;

    // stage A: f32 -> hi/lo bf16, swizzled LDS
    {
        int r  = tid >> 2;                 // 0..63
        int c0 = (tid & 3) * 32;
        int gr = row0 + r;
        bool ok = gr < NN;
        const float* src = A + (size_t)(ok ? gr : 0) * C + c0;
        #pragma unroll
        for (int g = 0; g < 4; ++g) {
            float f[8];
            if (ok) {
                *(float4*)&f[0] = *(const float4*)(src + g * 8);
                *(float4*)&f[4] = *(const float4*)(src + g * 8 + 4);
            } else {
                #pragma unroll
                for (int j = 0; j < 8; ++j) f[j] = 0.f;
            }
            union { unsigned short u[8]; uint4 v; } ph, pl;
            #pragma unroll
            for (int j = 0; j < 8; ++j) {
                unsigned short h = f2bf(f[j]);
                ph.u[j] = h;
                pl.u[j] = f2bf(f[j] - bf2f(h));
            }
            int k = c0 + g * 8;
            int byte = (r * 256 + k * 2) ^ ((r & 7) << 4);
            *(uint4*)((char*)Ah + byte) = ph.v;
            *(uint4*)((char*)Al + byte) = pl.v;
        }
    }

    bf16x8 bh[2][4], bl[2][4];
    #pragma unroll
    for (int cf = 0; cf < 2; ++cf) {
        int col = wv * 32 + cf * 16 + (lane & 15);
        #pragma unroll
        for (int kt = 0; kt < 4; ++kt) {
            int k = kt * 32 + (lane >> 4) * 8;
            bh[cf][kt] = *(const bf16x8*)(Bh + (size_t)col * C + k);
            bl[cf][kt] = *(const bf16x8*)(Bl + (size_t)col * C + k);
        }
    }

    __syncthreads();

    f32x4 zero = {0.f, 0.f, 0.f, 0.f};
    f32x4 acc[4][2];
    #pragma unroll
    for (int rf = 0; rf < 4; ++rf)
        #pragma unroll
        for (int cf = 0; cf < 2; ++cf) acc[rf][cf] = zero;

    #pragma unroll
    for (int rf = 0; rf < 4; ++rf) {
        int row = rf * 16 + (lane & 15);
        #pragma unroll
        for (int kt = 0; kt < 4; ++kt) {
            int k = kt * 32 + (lane >> 4) * 8;
            int byte = (row * 256 + k * 2) ^ ((row & 7) << 4);
            bf16x8 ah = *(const bf16x8*)((const char*)Ah + byte);
            bf16x8 al = *(const bf16x8*)((const char*)Al + byte);
            #pragma unroll
            for (int cf = 0; cf < 2; ++cf) {
                acc[rf][cf] = __builtin_amdgcn_mfma_f32_16x16x32_bf16(ah, bh[cf][kt], acc[rf][cf], 0, 0, 0);
                acc[rf][cf] = __builtin_amdgcn_mfma_f32_16x16x32_bf16(al, bh[cf][kt], acc[rf][cf], 0, 0, 0);
                acc[rf][cf] = __builtin_amdgcn_mfma_f32_16x16x32_bf16(ah, bl[cf][kt], acc[rf][cf], 0, 0, 0);
            }
        }
    }

    #pragma unroll
    for (int cf = 0; cf < 2; ++cf) {
        int col = wv * 32 + cf * 16 + (lane & 15);
        #pragma unroll
        for (int rf = 0; rf < 4; ++rf) {
            #pragma unroll
            for (int q = 0; q < 4; ++q) {
                int row = row0 + rf * 16 + (lane >> 4) * 4 + q;
                if (row < NN) G[(size_t)row * C + col] = f2bf(acc[rf][cf][q]);
            }
        }
    }
}

// ---------------------------------------------------------------------------
// k_mm2: G = A @ W for one or two chains (A bf16 plane exact -> 2-term MFMA).
// grid = nblk (single) or 2*nblk (dual: blockIdx>=nblk -> chain 1).
// ---------------------------------------------------------------------------

__global__ __launch_bounds__(256) void k_mm2(const unsigned short* __restrict__ Ap,
                                             const unsigned short* __restrict__ An,
                                             const unsigned short* __restrict__ Bh,
                                             const unsigned short* __restrict__ Bl,
                                             unsigned short* __restrict__ Gp,
                                             unsigned short* __restrict__ Gn, int nblk) {
    __shared__ unsigned short Ah[64 * 128];
    int tid  = threadIdx.x;
    int lane = tid & 63;
    int wv   = tid >> 6;
    int chain = blockIdx.x >= nblk;
    int blk   = chain ? blockIdx.x - nblk : blockIdx.x;
    const unsigned short* A = chain ? An : Ap;
    unsigned short*       G = chain ? Gn : Gp;
    int row0 = blk * 64;

    {
        int r  = tid >> 2;
        int c0 = (tid & 3) * 32;
        int gr = row0 + r;
        bool ok = gr < NN;
        const unsigned short* s = A + (size_t)(ok ? gr : 0) * C + c0;
        #pragma unroll
        for (int g = 0; g < 4; ++g) {
            uint4 v = ok ? *(const uint4*)(s + g * 8) : make_uint4(0, 0, 0, 0);
            int k = c0 + g * 8;
            int byte = (r * 256 + k * 2) ^ ((r & 7) << 4);
            *(uint4*)((char*)Ah + byte) = v;
        }
    }

    bf16x8 bh[2][4], bl[2][4];
    #pragma unroll
    for (int cf = 0; cf < 2; ++cf) {
        int col = wv * 32 + cf * 16 + (lane & 15);
        #pragma unroll
        for (int kt = 0; kt < 4; ++kt) {
            int k = kt * 32 + (lane >> 4) * 8;
            bh[cf][kt] = *(const bf16x8*)(Bh + (size_t)col * C + k);
            bl[cf][kt] = *(const bf16x8*)(Bl + (size_t)col * C + k);
        }
    }

    __syncthreads();

    f32x4 zero = {0.f, 0.f, 0.f, 0.f};
    f32x4 acc[4][2];
    #pragma unroll
    for (int rf = 0; rf < 4; ++rf)
        #pragma unroll
        for (int cf = 0; cf < 2; ++cf) acc[rf][cf] = zero;

    #pragma unroll
    for (int rf = 0; rf < 4; ++rf) {
        int row = rf * 16 + (lane & 15);
        #pragma unroll
        for (int kt = 0; kt < 4; ++kt) {
            int k = kt * 32 + (lane >> 4) * 8;
            int byte = (row * 256 + k * 2) ^ ((row & 7) << 4);
            bf16x8 a = *(const bf16x8*)((const char*)Ah + byte);
            #pragma unroll
            for (int cf = 0; cf < 2; ++cf) {
                acc[rf][cf] = __builtin_amdgcn_mfma_f32_16x16x32_bf16(a, bh[cf][kt], acc[rf][cf], 0, 0, 0);
                acc[rf][cf] = __builtin_amdgcn_mfma_f32_16x16x32_bf16(a, bl[cf][kt], acc[rf][cf], 0, 0, 0);
            }
        }
    }

    #pragma unroll
    for (int cf = 0; cf < 2; ++cf) {
        int col = wv * 32 + cf * 16 + (lane & 15);
        #pragma unroll
        for (int rf = 0; rf < 4; ++rf) {
            #pragma unroll
            for (int q = 0; q < 4; ++q) {
                int row = row0 + rf * 16 + (lane >> 4) * 4 + q;
                if (row < NN) G[(size_t)row * C + col] = f2bf(acc[rf][cf][q]);
            }
        }
    }
}

// ---------------------------------------------------------------------------
// k_agg2: out[i] = sum_{e:dst=i} G[src]*w + G[i]*dinv^2 + bias  [+PReLU]
// for one or two chains (grid = nb or 2*nb). Round-7 v4 gather structure:
// one wave/node, em staged to wave-private LDS, 4 lane-groups x 16B gathers.
// Epilogue: +bias (+PReLU); g0 writes bf16 plane, g1/g2 write f32 row.
// permN applies to chain 1 only (layer-1 corruption on shared G).
// ---------------------------------------------------------------------------

__global__ __launch_bounds__(256) void k_agg2(const unsigned short* __restrict__ Gp,
                                              const unsigned short* __restrict__ Gn,
                                              const int* __restrict__ permN,
                                              const float* __restrict__ dinv,
                                              const unsigned* __restrict__ off,
                                              const uint2* __restrict__ em,
                                              const float* __restrict__ bias,
                                              const float* __restrict__ prelu,
                                              unsigned short* planeP, unsigned short* planeN,
                                              float* fP, float* fN, int nb) {
    __shared__ uint2 sem[4][64];          // per-wave edge staging (2KB)
    int tid   = threadIdx.x;
    int chain = blockIdx.x >= nb;
    int blk   = chain ? blockIdx.x - nb : blockIdx.x;
    int i     = (blk * 256 + tid) >> 6;
    int lane  = tid & 63;
    int wid   = tid >> 6;
    if (i >= NN) return;
    const unsigned short* Gsel = chain ? Gn : Gp;
    const int*            prm  = chain ? permN : nullptr;
    int g  = lane >> 4;
    int il = lane & 15;
    const uint4* H4 = (const uint4*)Gsel;

    float a[8];
    {
        int si = prm ? prm[i] : i;
        uint4 hv = H4[(size_t)si * 16 + il];
        float dv = dinv[i];
        float sn = (g == 0) ? dv * dv : 0.f;
        a[0] = __uint_as_float(hv.x << 16) * sn;
        a[1] = __uint_as_float(hv.x & 0xffff0000u) * sn;
        a[2] = __uint_as_float(hv.y << 16) * sn;
        a[3] = __uint_as_float(hv.y & 0xffff0000u) * sn;
        a[4] = __uint_as_float(hv.z << 16) * sn;
        a[5] = __uint_as_float(hv.z & 0xffff0000u) * sn;
        a[6] = __uint_as_float(hv.w << 16) * sn;
        a[7] = __uint_as_float(hv.w & 0xffff0000u) * sn;
    }

    unsigned p0 = off[i], p1 = off[i + 1];
    for (unsigned base = p0; base < p1; base += 64) {
        unsigned rem = p1 - base;
        int cap = rem < 64u ? (int)rem : 64;
        sem[wid][lane] = em[base + ((unsigned)lane < rem ? (unsigned)lane : 0u)];
        #pragma unroll 4
        for (int t = g; t < cap; t += 4) {
            uint2 e = sem[wid][t];
            unsigned sv = e.x;
            if (prm) sv = (unsigned)prm[sv];
            float wv = __uint_as_float(e.y);
            uint4 hv = H4[(size_t)sv * 16 + il];
            a[0] += __uint_as_float(hv.x << 16) * wv;
            a[1] += __uint_as_float(hv.x & 0xffff0000u) * wv;
            a[2] += __uint_as_float(hv.y << 16) * wv;
            a[3] += __uint_as_float(hv.y & 0xffff0000u) * wv;
            a[4] += __uint_as_float(hv.z << 16) * wv;
            a[5] += __uint_as_float(hv.z & 0xffff0000u) * wv;
            a[6] += __uint_as_float(hv.w << 16) * wv;
            a[7] += __uint_as_float(hv.w & 0xffff0000u) * wv;
        }
    }

    #pragma unroll
    for (int j = 0; j < 8; ++j) {
        a[j] += __shfl_xor(a[j], 16, 64);
        a[j] += __shfl_xor(a[j], 32, 64);
    }

    // bias + PReLU (a[] bit-identical across groups)
    {
        float bv[8];
        *(float4*)&bv[0] = *(const float4*)(bias + il * 8);
        *(float4*)&bv[4] = *(const float4*)(bias + il * 8 + 4);
        #pragma unroll
        for (int j = 0; j < 8; ++j) a[j] += bv[j];
        if (prelu) {
            float pv[8];
            *(float4*)&pv[0] = *(const float4*)(prelu + il * 8);
            *(float4*)&pv[4] = *(const float4*)(prelu + il * 8 + 4);
            #pragma unroll
            for (int j = 0; j < 8; ++j) a[j] = (a[j] >= 0.f) ? a[j] : pv[j] * a[j];
        }
    }

    unsigned short* plane = chain ? planeN : planeP;
    float*          fo    = chain ? fN : fP;
    if (g == 0 && plane) {
        uint4 o;
        o.x = (unsigned)f2bf(a[0]) | ((unsigned)f2bf(a[1]) << 16);
        o.y = (unsigned)f2bf(a[2]) | ((unsigned)f2bf(a[3]) << 16);
        o.z = (unsigned)f2bf(a[4]) | ((unsigned)f2bf(a[5]) << 16);
        o.w = (unsigned)f2bf(a[6]) | ((unsigned)f2bf(a[7]) << 16);
        ((uint4*)plane)[(size_t)i * 16 + il] = o;
    }
    if (fo) {
        if (g == 1) *(float4*)(fo + (size_t)i * C + il * 8)     = make_float4(a[0], a[1], a[2], a[3]);
        if (g == 2) *(float4*)(fo + (size_t)i * C + il * 8 + 4) = make_float4(a[4], a[5], a[6], a[7]);
    }
}

// ---------------------------------------------------------------------------
// summary = sigmoid(mean(pos_z, axis=0))
// ---------------------------------------------------------------------------

__global__ __launch_bounds__(256) void k_sum(const float* __restrict__ pos, float* sumbuf) {
    __shared__ float red[256];
    int t = threadIdx.x;
    int c = t & 127;
    int half = t >> 7;
    float acc = 0.f;
    for (int r = blockIdx.x * 2 + half; r < NN; r += gridDim.x * 2)
        acc += pos[(size_t)r * C + c];
    red[t] = acc;
    __syncthreads();
    if (half == 0) atomicAdd(&sumbuf[c], acc + red[t + 128]);
}

__global__ void k_summary(const float* sumbuf, float* out) {
    int t = threadIdx.x;
    if (t < C) {
        float m = sumbuf[t] * (1.0f / (float)NN);
        out[t] = 1.0f / (1.0f + expf(-m));
    }
}

// ---------------------------------------------------------------------------
// q: Student's-t soft assignment. 256 thr: 64 nodes, 4 threads/node.
// ---------------------------------------------------------------------------

__global__ __launch_bounds__(256) void k_q(const float* __restrict__ xo,
                                           const float* __restrict__ mu,
                                           float* __restrict__ qout) {
    __shared__ float sx[64][132];
    __shared__ float smu[KC][128];
    __shared__ float smun[KC];
    int tid = threadIdx.x;
    for (int idx = tid; idx < KC * 128; idx += 256)
        smu[idx >> 7][idx & 127] = mu[idx];
    __syncthreads();
    if (tid < KC) {
        float s = 0.f;
        #pragma unroll 4
        for (int j = 0; j < 128; ++j) { float m = smu[tid][j]; s += m * m; }
        smun[tid] = s;
    }
    int n0 = blockIdx.x * 64;
    for (int idx = tid; idx < 64 * 32; idx += 256) {
        int r = idx >> 5;
        int c = (idx & 31) * 4;
        int gr = n0 + r;
        float4 v = make_float4(0.f, 0.f, 0.f, 0.f);
        if (gr < NN) v = *(const float4*)(xo + (size_t)gr * C + c);
        *(float4*)&sx[r][c] = v;
    }
    __syncthreads();
    int lr = tid >> 2;
    int g  = tid & 3;
    int node = n0 + lr;
    if (node < NN) {
        float ss = 0.f;
        #pragma unroll 8
        for (int j = 0; j < 128; ++j) { float x = sx[lr][j]; ss += x * x; }
        float qv[5]; float qs = 0.f;
        #pragma unroll
        for (int kk = 0; kk < 5; ++kk) {
            int k = g * 5 + kk;
            float dot = 0.f;
            #pragma unroll 8
            for (int j = 0; j < 128; ++j) dot += sx[lr][j] * smu[k][j];
            float d = ss + smun[k] - 2.0f * dot;
            d = fmaxf(d, 0.f);
            float q = 1.0f / (1.0f + d * 5.0f + 1e-8f);
            q = powf(q, 1.2f) * 0.5f;
            qv[kk] = q; qs += q;
        }
        qs += __shfl_xor(qs, 1, 64);
        qs += __shfl_xor(qs, 2, 64);
        float inv = 1.0f / qs;
        #pragma unroll
        for (int kk = 0; kk < 5; ++kk)
            qout[(size_t)node * KC + g * 5 + kk] = qv[kk] * inv;
    }
}

// ---------------------------------------------------------------------------
// launch
// ---------------------------------------------------------------------------

extern "C" void kernel_launch(void* const* d_in, const int* in_sizes, int n_in,
                              void* d_out, int out_size, void* d_ws, size_t ws_size,
                              hipStream_t stream) {
    const float* x    = (const float*)d_in[0];
    const int*   ei   = (const int*)d_in[1];
    const float* ew   = (const float*)d_in[2];
    const int*   perm = (const int*)d_in[3];
    const float* W1 = (const float*)d_in[4];  const float* b1 = (const float*)d_in[5];
    const float* W2 = (const float*)d_in[6];  const float* b2 = (const float*)d_in[7];
    const float* W3 = (const float*)d_in[8];  const float* b3 = (const float*)d_in[9];
    const float* W4 = (const float*)d_in[10]; const float* b4 = (const float*)d_in[11];
    const float* prelu_a = (const float*)d_in[12];
    const float* Wc = (const float*)d_in[13]; const float* bc = (const float*)d_in[14];
    const float* mu = (const float*)d_in[15];

    float* out     = (float*)d_out;
    float* pos_z   = out;                          // [N,128]
    float* neg_z   = out + (size_t)NN * C;         // [N,128]
    float* summary = out + (size_t)2 * NN * C;     // [128]
    float* xout    = summary + C;                  // [N,128]
    float* qout    = xout + (size_t)NN * C;        // [N,20]

    // workspace carve (~71 MB)
    char* w = (char*)d_ws;
    auto carve = [&](size_t bytes) { void* p = (void*)w; w += (bytes + 511) & ~(size_t)511; return p; };
    float*          dinv   = (float*)carve((size_t)NN * 4);
    unsigned*       cnt    = (unsigned*)carve((size_t)(NN + 1) * 4);  // -> off in place
    unsigned*       cursor = (unsigned*)carve((size_t)NN * 4);
    unsigned*       bsum   = (unsigned*)carve(256 * 4);
    unsigned*       total  = (unsigned*)carve(64);
    uint2*          em     = (uint2*)carve((size_t)EE * 8);           // (src, w)
    float*          sumbuf = (float*)carve(512);
    unsigned short* wt     = (unsigned short*)carve((size_t)5 * 2 * C * C * 2);
    unsigned short* Gp     = (unsigned short*)carve((size_t)NN * C * 2);
    unsigned short* Gn     = (unsigned short*)carve((size_t)NN * C * 2);
    unsigned short* P0     = (unsigned short*)carve((size_t)NN * C * 2);
    unsigned short* P1     = (unsigned short*)carve((size_t)NN * C * 2);
    unsigned short* P2     = (unsigned short*)carve((size_t)NN * C * 2);

    unsigned short* Wh[5], *Wl[5];
    for (int m = 0; m < 5; ++m) {
        Wh[m] = wt + (size_t)(2 * m) * C * C;
        Wl[m] = wt + (size_t)(2 * m + 1) * C * C;
    }

    hipMemsetAsync(cnt, 0, (size_t)(NN + 1) * 4, stream);
    hipMemsetAsync(sumbuf, 0, 512, stream);

    int gE = (EE + 255) / 256, gN = (NN + 255) / 256;

    // graph build
    k_hist <<<gE, 256, 0, stream>>>(ei, cnt);
    k_scan1<<<NB, 256, 0, stream>>>(cnt, bsum);
    k_scan2<<<1, 64, 0, stream>>>(bsum, total);
    k_scan3<<<NB, 256, 0, stream>>>(cnt, bsum, total, cnt, cursor);   // cnt := off
    k_fill <<<gE, 256, 0, stream>>>(ei, ew, cursor, em);
    k_dinv_csr<<<gN, 256, 0, stream>>>(cnt, em, dinv);
    k_scale<<<gN, 256, 0, stream>>>(cnt, dinv, em);

    // weight split/transpose
    k_wsplit<<<320, 256, 0, stream>>>(W1, W2, W3, W4, Wc, wt);

    int gM = (NN + 63) / 64;      // 782 blocks per chain (mm)
    int gA = (NN + 3) / 4;        // 12500 blocks per chain (agg)

    // Layer 1: G1 = x@W1 shared by pos & neg ((xW1)[perm] == (x[perm])W1)
    k_mm_f32<<<gM, 256, 0, stream>>>(x, Wh[0], Wl[0], Gp);
    k_agg2<<<2 * gA, 256, 0, stream>>>(Gp, Gp, perm, dinv, cnt, em, b1, nullptr,
                                       P0, P1, nullptr, nullptr, gA);
    // Layers 2-3 (dual-chain)
    k_mm2 <<<2 * gM, 256, 0, stream>>>(P0, P1, Wh[1], Wl[1], Gp, Gn, gM);
    k_agg2<<<2 * gA, 256, 0, stream>>>(Gp, Gn, nullptr, dinv, cnt, em, b2, nullptr,
                                       P0, P1, nullptr, nullptr, gA);
    k_mm2 <<<2 * gM, 256, 0, stream>>>(P0, P1, Wh[2], Wl[2], Gp, Gn, gM);
    k_agg2<<<2 * gA, 256, 0, stream>>>(Gp, Gn, nullptr, dinv, cnt, em, b3, nullptr,
                                       P0, P1, nullptr, nullptr, gA);
    // Layer 4 (PReLU; pos writes f32 + plane for decoder, neg writes f32)
    k_mm2 <<<2 * gM, 256, 0, stream>>>(P0, P1, Wh[3], Wl[3], Gp, Gn, gM);
    k_agg2<<<2 * gA, 256, 0, stream>>>(Gp, Gn, nullptr, dinv, cnt, em, b4, prelu_a,
                                       P2, nullptr, pos_z, neg_z, gA);
    // Decoder: xout = Â(pos_z@Wc) + bc
    k_mm2 <<<gM, 256, 0, stream>>>(P2, P2, Wh[4], Wl[4], Gp, Gn, gM);
    k_agg2<<<gA, 256, 0, stream>>>(Gp, Gp, nullptr, dinv, cnt, em, bc, nullptr,
                                   nullptr, nullptr, xout, nullptr, gA);

    // summary
    k_sum<<<256, 256, 0, stream>>>(pos_z, sumbuf);
    k_summary<<<1, 128, 0, stream>>>(sumbuf, summary);

    // q soft assignment
    k_q<<<(NN + 63) / 64, 256, 0, stream>>>(xout, mu, qout);
}

// Round 9
// 595.313 us; speedup vs baseline: 2.4985x; 1.0086x over previous
//
#include <hip/hip_runtime.h>
#include <hip/hip_bf16.h>

// Problem constants (from reference)
constexpr int NN = 50000;   // nodes
constexpr int EE = 800000;  // edges
constexpr int C  = 128;     // channels (IN == H == 128)
constexpr int KC = 20;      // clusters
constexpr int NB = (NN + 1023) / 1024;   // scan blocks (49)

typedef __attribute__((ext_vector_type(8))) short bf16x8;   // 8 bf16 (4 VGPRs)
typedef __attribute__((ext_vector_type(4))) float f32x4;

__device__ inline unsigned short f2bf(float f) {            // RN f32->bf16
    unsigned u = __float_as_uint(f);
    u += 0x7fff + ((u >> 16) & 1);
    return (unsigned short)(u >> 16);
}
__device__ inline float bf2f(unsigned short h) {
    return __uint_as_float(((unsigned)h) << 16);
}

// ---------------------------------------------------------------------------
// Graph preprocessing (int inputs are int32 on device)
// ---------------------------------------------------------------------------

__global__ void k_hist(const int* __restrict__ ei, unsigned* cnt) {
    int e = blockIdx.x * 256 + threadIdx.x;
    if (e >= EE) return;
    atomicAdd(&cnt[ei[EE + e]], 1u);
}

__global__ __launch_bounds__(256) void k_scan1(const unsigned* __restrict__ cnt,
                                               unsigned* __restrict__ bsum) {
    __shared__ unsigned red[256];
    int b = blockIdx.x, t = threadIdx.x;
    int i0 = b * 1024 + t * 4;
    unsigned s = 0;
    #pragma unroll
    for (int j = 0; j < 4; ++j) { int i = i0 + j; s += (i < NN) ? cnt[i] : 0u; }
    red[t] = s; __syncthreads();
    for (int st = 128; st > 0; st >>= 1) { if (t < st) red[t] += red[t + st]; __syncthreads(); }
    if (t == 0) bsum[b] = red[0];
}

__global__ void k_scan2(unsigned* bsum, unsigned* total) {   // 1 block, 64 thr
    int t = threadIdx.x;
    unsigned v = (t < NB) ? bsum[t] : 0u;
    unsigned x = v;
    #pragma unroll
    for (int s = 1; s < 64; s <<= 1) { unsigned u = __shfl_up(x, s, 64); if (t >= s) x += u; }
    if (t < NB) bsum[t] = x - v;     // exclusive block offset
    if (t == 63) *total = x;
}

__global__ __launch_bounds__(256) void k_scan3(const unsigned* __restrict__ cnt,
                                               const unsigned* __restrict__ bsum,
                                               const unsigned* __restrict__ total,
                                               unsigned* __restrict__ off,
                                               unsigned* __restrict__ cursor) {
    __shared__ unsigned wred[4];
    int b = blockIdx.x, t = threadIdx.x, lane = t & 63, wv = t >> 6;
    int i0 = b * 1024 + t * 4;
    unsigned v[4]; unsigned s = 0;
    #pragma unroll
    for (int j = 0; j < 4; ++j) { int i = i0 + j; v[j] = (i < NN) ? cnt[i] : 0u; s += v[j]; }
    unsigned x = s;
    #pragma unroll
    for (int st = 1; st < 64; st <<= 1) { unsigned u = __shfl_up(x, st, 64); if (lane >= st) x += u; }
    if (lane == 63) wred[wv] = x;
    __syncthreads();
    unsigned woff = 0;
    for (int k = 0; k < 4; ++k) if (k < wv) woff += wred[k];
    unsigned excl = bsum[b] + woff + x - s;
    #pragma unroll
    for (int j = 0; j < 4; ++j) {
        int i = i0 + j;
        if (i < NN) { off[i] = excl; cursor[i] = excl; excl += v[j]; }
    }
    if (b == 0 && t == 0) off[NN] = *total;
}

// CSR fill: interleaved edge meta (src, raw weight) — one 8B store per edge
__global__ void k_fill(const int* __restrict__ ei, const float* __restrict__ ew,
                       unsigned* cursor, uint2* __restrict__ em) {
    int e = blockIdx.x * 256 + threadIdx.x;
    if (e >= EE) return;
    int s = ei[e];
    int d = ei[EE + e];
    unsigned p = atomicAdd(&cursor[d], 1u);
    em[p] = make_uint2((unsigned)s, __float_as_uint(ew[e]));
}

// deg[i] = 1 + sum(raw weights of row i); dinv = rsqrt
__global__ void k_dinv_csr(const unsigned* __restrict__ off,
                           const uint2* __restrict__ em, float* __restrict__ dinv) {
    int i = blockIdx.x * 256 + threadIdx.x;
    if (i >= NN) return;
    unsigned p0 = off[i], p1 = off[i + 1];
    float s = 1.0f;                       // self-loop weight
    for (unsigned p = p0; p < p1; ++p) s += __uint_as_float(em[p].y);
    dinv[i] = (s > 0.f) ? rsqrtf(s) : 0.f;
}

// em[p].w *= dinv[src]*dinv[dst]
__global__ void k_scale(const unsigned* __restrict__ off, const float* __restrict__ dinv,
                        uint2* __restrict__ em) {
    int i = blockIdx.x * 256 + threadIdx.x;
    if (i >= NN) return;
    float di = dinv[i];
    unsigned p0 = off[i], p1 = off[i + 1];
    for (unsigned p = p0; p < p1; ++p) {
        uint2 e = em[p];
        em[p].y = __float_as_uint(dinv[e.x] * __uint_as_float(e.y) * di);
    }
}

// ---------------------------------------------------------------------------
// Weight preconversion: 5 mats W[128][128] f32 -> Wt_hi/lo[col][k] bf16 (W^T)
// ---------------------------------------------------------------------------

__global__ void k_wsplit(const float* W0, const float* W1, const float* W2,
                         const float* W3, const float* W4,
                         unsigned short* __restrict__ wt) {
    int m = blockIdx.x >> 6;
    const float* W = (m == 0) ? W0 : (m == 1) ? W1 : (m == 2) ? W2 : (m == 3) ? W3 : W4;
    int idx = (blockIdx.x & 63) * 256 + threadIdx.x;   // 0..16383
    int k = idx >> 7, j = idx & 127;
    float v = W[idx];
    unsigned short h = f2bf(v);
    unsigned short* hi = wt + (size_t)(2 * m) * C * C;
    unsigned short* lo = wt + (size_t)(2 * m + 1) * C * C;
    hi[j * C + k] = h;
    lo[j * C + k] = f2bf(v - bf2f(h));
}

// ---------------------------------------------------------------------------
// k_mm_f32: G = x @ W (x f32, 3-term hi/lo split) -> bf16 plane. Layer-1 only.
// ---------------------------------------------------------------------------

__global__ __launch_bounds__(256) void k_mm_f32(const float* __restrict__ A,
                                                const unsigned short* __restrict__ Bh,
                                                const unsigned short* __restrict__ Bl,
                                                unsigned short* __restrict__ G) {
    __shared__ unsigned short Ah[64 * 128];
    __shared__ unsigned short Al[64 * 128];
    int tid  = threadIdx.x;
    int lane = tid & 63;
    int wv   = tid >> 6;
    int row0 = blockIdx.x * 64;

    // stage A: f32 -> hi/lo bf16, swizzled LDS
    {
        int r  = tid >> 2;                 // 0..63
        int c0 = (tid & 3) * 32;
        int gr = row0 + r;
        bool ok = gr < NN;
        const float* src = A + (size_t)(ok ? gr : 0) * C + c0;
        #pragma unroll
        for (int g = 0; g < 4; ++g) {
            float f[8];
            if (ok) {
                *(float4*)&f[0] = *(const float4*)(src + g * 8);
                *(float4*)&f[4] = *(const float4*)(src + g * 8 + 4);
            } else {
                #pragma unroll
                for (int j = 0; j < 8; ++j) f[j] = 0.f;
            }
            union { unsigned short u[8]; uint4 v; } ph, pl;
            #pragma unroll
            for (int j = 0; j < 8; ++j) {
                unsigned short h = f2bf(f[j]);
                ph.u[j] = h;
                pl.u[j] = f2bf(f[j] - bf2f(h));
            }
            int k = c0 + g * 8;
            int byte = (r * 256 + k * 2) ^ ((r & 7) << 4);
            *(uint4*)((char*)Ah + byte) = ph.v;
            *(uint4*)((char*)Al + byte) = pl.v;
        }
    }

    bf16x8 bh[2][4], bl[2][4];
    #pragma unroll
    for (int cf = 0; cf < 2; ++cf) {
        int col = wv * 32 + cf * 16 + (lane & 15);
        #pragma unroll
        for (int kt = 0; kt < 4; ++kt) {
            int k = kt * 32 + (lane >> 4) * 8;
            bh[cf][kt] = *(const bf16x8*)(Bh + (size_t)col * C + k);
            bl[cf][kt] = *(const bf16x8*)(Bl + (size_t)col * C + k);
        }
    }

    __syncthreads();

    f32x4 zero = {0.f, 0.f, 0.f, 0.f};
    f32x4 acc[4][2];
    #pragma unroll
    for (int rf = 0; rf < 4; ++rf)
        #pragma unroll
        for (int cf = 0; cf < 2; ++cf) acc[rf][cf] = zero;

    #pragma unroll
    for (int rf = 0; rf < 4; ++rf) {
        int row = rf * 16 + (lane & 15);
        #pragma unroll
        for (int kt = 0; kt < 4; ++kt) {
            int k = kt * 32 + (lane >> 4) * 8;
            int byte = (row * 256 + k * 2) ^ ((row & 7) << 4);
            bf16x8 ah = *(const bf16x8*)((const char*)Ah + byte);
            bf16x8 al = *(const bf16x8*)((const char*)Al + byte);
            #pragma unroll
            for (int cf = 0; cf < 2; ++cf) {
                acc[rf][cf] = __builtin_amdgcn_mfma_f32_16x16x32_bf16(ah, bh[cf][kt], acc[rf][cf], 0, 0, 0);
                acc[rf][cf] = __builtin_amdgcn_mfma_f32_16x16x32_bf16(al, bh[cf][kt], acc[rf][cf], 0, 0, 0);
                acc[rf][cf] = __builtin_amdgcn_mfma_f32_16x16x32_bf16(ah, bl[cf][kt], acc[rf][cf], 0, 0, 0);
            }
        }
    }

    #pragma unroll
    for (int cf = 0; cf < 2; ++cf) {
        int col = wv * 32 + cf * 16 + (lane & 15);
        #pragma unroll
        for (int rf = 0; rf < 4; ++rf) {
            #pragma unroll
            for (int q = 0; q < 4; ++q) {
                int row = row0 + rf * 16 + (lane >> 4) * 4 + q;
                if (row < NN) G[(size_t)row * C + col] = f2bf(acc[rf][cf][q]);
            }
        }
    }
}

// ---------------------------------------------------------------------------
// k_mm2: G = A @ W for one or two chains (A bf16 plane exact -> 2-term MFMA).
// grid = nblk (single) or 2*nblk (dual: blockIdx>=nblk -> chain 1).
// ---------------------------------------------------------------------------

__global__ __launch_bounds__(256) void k_mm2(const unsigned short* __restrict__ Ap,
                                             const unsigned short* __restrict__ An,
                                             const unsigned short* __restrict__ Bh,
                                             const unsigned short* __restrict__ Bl,
                                             unsigned short* __restrict__ Gp,
                                             unsigned short* __restrict__ Gn, int nblk) {
    __shared__ unsigned short Ah[64 * 128];
    int tid  = threadIdx.x;
    int lane = tid & 63;
    int wv   = tid >> 6;
    int chain = blockIdx.x >= nblk;
    int blk   = chain ? blockIdx.x - nblk : blockIdx.x;
    const unsigned short* A = chain ? An : Ap;
    unsigned short*       G = chain ? Gn : Gp;
    int row0 = blk * 64;

    {
        int r  = tid >> 2;
        int c0 = (tid & 3) * 32;
        int gr = row0 + r;
        bool ok = gr < NN;
        const unsigned short* s = A + (size_t)(ok ? gr : 0) * C + c0;
        #pragma unroll
        for (int g = 0; g < 4; ++g) {
            uint4 v = ok ? *(const uint4*)(s + g * 8) : make_uint4(0, 0, 0, 0);
            int k = c0 + g * 8;
            int byte = (r * 256 + k * 2) ^ ((r & 7) << 4);
            *(uint4*)((char*)Ah + byte) = v;
        }
    }

    bf16x8 bh[2][4], bl[2][4];
    #pragma unroll
    for (int cf = 0; cf < 2; ++cf) {
        int col = wv * 32 + cf * 16 + (lane & 15);
        #pragma unroll
        for (int kt = 0; kt < 4; ++kt) {
            int k = kt * 32 + (lane >> 4) * 8;
            bh[cf][kt] = *(const bf16x8*)(Bh + (size_t)col * C + k);
            bl[cf][kt] = *(const bf16x8*)(Bl + (size_t)col * C + k);
        }
    }

    __syncthreads();

    f32x4 zero = {0.f, 0.f, 0.f, 0.f};
    f32x4 acc[4][2];
    #pragma unroll
    for (int rf = 0; rf < 4; ++rf)
        #pragma unroll
        for (int cf = 0; cf < 2; ++cf) acc[rf][cf] = zero;

    #pragma unroll
    for (int rf = 0; rf < 4; ++rf) {
        int row = rf * 16 + (lane & 15);
        #pragma unroll
        for (int kt = 0; kt < 4; ++kt) {
            int k = kt * 32 + (lane >> 4) * 8;
            int byte = (row * 256 + k * 2) ^ ((row & 7) << 4);
            bf16x8 a = *(const bf16x8*)((const char*)Ah + byte);
            #pragma unroll
            for (int cf = 0; cf < 2; ++cf) {
                acc[rf][cf] = __builtin_amdgcn_mfma_f32_16x16x32_bf16(a, bh[cf][kt], acc[rf][cf], 0, 0, 0);
                acc[rf][cf] = __builtin_amdgcn_mfma_f32_16x16x32_bf16(a, bl[cf][kt], acc[rf][cf], 0, 0, 0);
            }
        }
    }

    #pragma unroll
    for (int cf = 0; cf < 2; ++cf) {
        int col = wv * 32 + cf * 16 + (lane & 15);
        #pragma unroll
        for (int rf = 0; rf < 4; ++rf) {
            #pragma unroll
            for (int q = 0; q < 4; ++q) {
                int row = row0 + rf * 16 + (lane >> 4) * 4 + q;
                if (row < NN) G[(size_t)row * C + col] = f2bf(acc[rf][cf][q]);
            }
        }
    }
}

// ---------------------------------------------------------------------------
// k_agg2 v5: out[i] = sum_{e:dst=i} G[src]*w + G[i]*dinv^2 + bias  [+PReLU]
// for one or two chains (grid = nb or 2*nb).
// TWO nodes per wave (half-wave each): halves per-node fixed overhead vs v4.
// Per node: 2 gather groups of 16 lanes (full 256B row, uint4/lane); edge
// metas staged per 32-edge batch into wave-private LDS (one 8B/lane load).
// Single xor-16 butterfly combines the 2 groups. Epilogue: bias (+PReLU);
// gg0 writes bf16 plane row; gg0/gg1 write f32 row halves.
// ---------------------------------------------------------------------------

__global__ __launch_bounds__(256) void k_agg2(const unsigned short* __restrict__ Gp,
                                              const unsigned short* __restrict__ Gn,
                                              const int* __restrict__ permN,
                                              const float* __restrict__ dinv,
                                              const unsigned* __restrict__ off,
                                              const uint2* __restrict__ em,
                                              const float* __restrict__ bias,
                                              const float* __restrict__ prelu,
                                              unsigned short* planeP, unsigned short* planeN,
                                              float* fP, float* fN, int nb) {
    __shared__ uint2 sem[4][64];          // per-wave edge staging (2KB)
    int tid   = threadIdx.x;
    int chain = blockIdx.x >= nb;
    int blk   = chain ? blockIdx.x - nb : blockIdx.x;
    int lane  = tid & 63;
    int wid   = tid >> 6;
    int half  = lane >> 5;                // node within wave (0/1)
    int gg    = (lane >> 4) & 1;          // gather group within node (0/1)
    int il    = lane & 15;                // channel block: ch il*8 .. il*8+7
    int l32   = lane & 31;
    int i     = (blk * 4 + wid) * 2 + half;
    bool act  = i < NN;
    const unsigned short* Gsel = chain ? Gn : Gp;
    const int*            prm  = chain ? permN : nullptr;
    const uint4* H4 = (const uint4*)Gsel;

    float a[8];
    // self term (gg==0 carries it; gg==1 contributes 0, fixed by butterfly)
    {
        int si = act ? (prm ? prm[i] : i) : 0;
        uint4 hv = H4[(size_t)si * 16 + il];
        float dv = act ? dinv[i] : 0.f;
        float sn = (gg == 0) ? dv * dv : 0.f;
        a[0] = __uint_as_float(hv.x << 16) * sn;
        a[1] = __uint_as_float(hv.x & 0xffff0000u) * sn;
        a[2] = __uint_as_float(hv.y << 16) * sn;
        a[3] = __uint_as_float(hv.y & 0xffff0000u) * sn;
        a[4] = __uint_as_float(hv.z << 16) * sn;
        a[5] = __uint_as_float(hv.z & 0xffff0000u) * sn;
        a[6] = __uint_as_float(hv.w << 16) * sn;
        a[7] = __uint_as_float(hv.w & 0xffff0000u) * sn;
    }

    unsigned p0 = 0, p1 = 0;
    if (act) { p0 = off[i]; p1 = off[i + 1]; }
    for (unsigned base = p0; base < p1; base += 32) {
        unsigned rem = p1 - base;
        int cap = rem < 32u ? (int)rem : 32;
        // stage this node's next <=32 edges into its half of the wave slot
        sem[wid][half * 32 + l32] = em[base + ((unsigned)l32 < rem ? (unsigned)l32 : 0u)];
        #pragma unroll 4
        for (int t = gg; t < cap; t += 2) {
            uint2 e = sem[wid][half * 32 + t];   // group-uniform broadcast
            unsigned sv = e.x;
            if (prm) sv = (unsigned)prm[sv];
            float wv = __uint_as_float(e.y);
            uint4 hv = H4[(size_t)sv * 16 + il];
            a[0] += __uint_as_float(hv.x << 16) * wv;
            a[1] += __uint_as_float(hv.x & 0xffff0000u) * wv;
            a[2] += __uint_as_float(hv.y << 16) * wv;
            a[3] += __uint_as_float(hv.y & 0xffff0000u) * wv;
            a[4] += __uint_as_float(hv.z << 16) * wv;
            a[5] += __uint_as_float(hv.z & 0xffff0000u) * wv;
            a[6] += __uint_as_float(hv.w << 16) * wv;
            a[7] += __uint_as_float(hv.w & 0xffff0000u) * wv;
        }
    }

    // combine the 2 groups (lanes il and il+16 within each half)
    #pragma unroll
    for (int j = 0; j < 8; ++j)
        a[j] += __shfl_xor(a[j], 16, 64);

    // bias + PReLU (a[] bit-identical across the half's two groups)
    {
        float bv[8];
        *(float4*)&bv[0] = *(const float4*)(bias + il * 8);
        *(float4*)&bv[4] = *(const float4*)(bias + il * 8 + 4);
        #pragma unroll
        for (int j = 0; j < 8; ++j) a[j] += bv[j];
        if (prelu) {
            float pv[8];
            *(float4*)&pv[0] = *(const float4*)(prelu + il * 8);
            *(float4*)&pv[4] = *(const float4*)(prelu + il * 8 + 4);
            #pragma unroll
            for (int j = 0; j < 8; ++j) a[j] = (a[j] >= 0.f) ? a[j] : pv[j] * a[j];
        }
    }

    unsigned short* plane = chain ? planeN : planeP;
    float*          fo    = chain ? fN : fP;
    if (act) {
        if (gg == 0 && plane) {
            uint4 o;
            o.x = (unsigned)f2bf(a[0]) | ((unsigned)f2bf(a[1]) << 16);
            o.y = (unsigned)f2bf(a[2]) | ((unsigned)f2bf(a[3]) << 16);
            o.z = (unsigned)f2bf(a[4]) | ((unsigned)f2bf(a[5]) << 16);
            o.w = (unsigned)f2bf(a[6]) | ((unsigned)f2bf(a[7]) << 16);
            ((uint4*)plane)[(size_t)i * 16 + il] = o;
        }
        if (fo) {
            if (gg == 0) *(float4*)(fo + (size_t)i * C + il * 8)     = make_float4(a[0], a[1], a[2], a[3]);
            else         *(float4*)(fo + (size_t)i * C + il * 8 + 4) = make_float4(a[4], a[5], a[6], a[7]);
        }
    }
}

// ---------------------------------------------------------------------------
// summary = sigmoid(mean(pos_z, axis=0))
// ---------------------------------------------------------------------------

__global__ __launch_bounds__(256) void k_sum(const float* __restrict__ pos, float* sumbuf) {
    __shared__ float red[256];
    int t = threadIdx.x;
    int c = t & 127;
    int half = t >> 7;
    float acc = 0.f;
    for (int r = blockIdx.x * 2 + half; r < NN; r += gridDim.x * 2)
        acc += pos[(size_t)r * C + c];
    red[t] = acc;
    __syncthreads();
    if (half == 0) atomicAdd(&sumbuf[c], acc + red[t + 128]);
}

__global__ void k_summary(const float* sumbuf, float* out) {
    int t = threadIdx.x;
    if (t < C) {
        float m = sumbuf[t] * (1.0f / (float)NN);
        out[t] = 1.0f / (1.0f + expf(-m));
    }
}

// ---------------------------------------------------------------------------
// q: Student's-t soft assignment. 256 thr: 64 nodes, 4 threads/node.
// ---------------------------------------------------------------------------

__global__ __launch_bounds__(256) void k_q(const float* __restrict__ xo,
                                           const float* __restrict__ mu,
                                           float* __restrict__ qout) {
    __shared__ float sx[64][132];
    __shared__ float smu[KC][128];
    __shared__ float smun[KC];
    int tid = threadIdx.x;
    for (int idx = tid; idx < KC * 128; idx += 256)
        smu[idx >> 7][idx & 127] = mu[idx];
    __syncthreads();
    if (tid < KC) {
        float s = 0.f;
        #pragma unroll 4
        for (int j = 0; j < 128; ++j) { float m = smu[tid][j]; s += m * m; }
        smun[tid] = s;
    }
    int n0 = blockIdx.x * 64;
    for (int idx = tid; idx < 64 * 32; idx += 256) {
        int r = idx >> 5;
        int c = (idx & 31) * 4;
        int gr = n0 + r;
        float4 v = make_float4(0.f, 0.f, 0.f, 0.f);
        if (gr < NN) v = *(const float4*)(xo + (size_t)gr * C + c);
        *(float4*)&sx[r][c] = v;
    }
    __syncthreads();
    int lr = tid >> 2;
    int g  = tid & 3;
    int node = n0 + lr;
    if (node < NN) {
        float ss = 0.f;
        #pragma unroll 8
        for (int j = 0; j < 128; ++j) { float x = sx[lr][j]; ss += x * x; }
        float qv[5]; float qs = 0.f;
        #pragma unroll
        for (int kk = 0; kk < 5; ++kk) {
            int k = g * 5 + kk;
            float dot = 0.f;
            #pragma unroll 8
            for (int j = 0; j < 128; ++j) dot += sx[lr][j] * smu[k][j];
            float d = ss + smun[k] - 2.0f * dot;
            d = fmaxf(d, 0.f);
            float q = 1.0f / (1.0f + d * 5.0f + 1e-8f);
            q = powf(q, 1.2f) * 0.5f;
            qv[kk] = q; qs += q;
        }
        qs += __shfl_xor(qs, 1, 64);
        qs += __shfl_xor(qs, 2, 64);
        float inv = 1.0f / qs;
        #pragma unroll
        for (int kk = 0; kk < 5; ++kk)
            qout[(size_t)node * KC + g * 5 + kk] = qv[kk] * inv;
    }
}

// ---------------------------------------------------------------------------
// launch
// ---------------------------------------------------------------------------

extern "C" void kernel_launch(void* const* d_in, const int* in_sizes, int n_in,
                              void* d_out, int out_size, void* d_ws, size_t ws_size,
                              hipStream_t stream) {
    const float* x    = (const float*)d_in[0];
    const int*   ei   = (const int*)d_in[1];
    const float* ew   = (const float*)d_in[2];
    const int*   perm = (const int*)d_in[3];
    const float* W1 = (const float*)d_in[4];  const float* b1 = (const float*)d_in[5];
    const float* W2 = (const float*)d_in[6];  const float* b2 = (const float*)d_in[7];
    const float* W3 = (const float*)d_in[8];  const float* b3 = (const float*)d_in[9];
    const float* W4 = (const float*)d_in[10]; const float* b4 = (const float*)d_in[11];
    const float* prelu_a = (const float*)d_in[12];
    const float* Wc = (const float*)d_in[13]; const float* bc = (const float*)d_in[14];
    const float* mu = (const float*)d_in[15];

    float* out     = (float*)d_out;
    float* pos_z   = out;                          // [N,128]
    float* neg_z   = out + (size_t)NN * C;         // [N,128]
    float* summary = out + (size_t)2 * NN * C;     // [128]
    float* xout    = summary + C;                  // [N,128]
    float* qout    = xout + (size_t)NN * C;        // [N,20]

    // workspace carve (~71 MB)
    char* w = (char*)d_ws;
    auto carve = [&](size_t bytes) { void* p = (void*)w; w += (bytes + 511) & ~(size_t)511; return p; };
    float*          dinv   = (float*)carve((size_t)NN * 4);
    unsigned*       cnt    = (unsigned*)carve((size_t)(NN + 1) * 4);  // -> off in place
    unsigned*       cursor = (unsigned*)carve((size_t)NN * 4);
    unsigned*       bsum   = (unsigned*)carve(256 * 4);
    unsigned*       total  = (unsigned*)carve(64);
    uint2*          em     = (uint2*)carve((size_t)EE * 8);           // (src, w)
    float*          sumbuf = (float*)carve(512);
    unsigned short* wt     = (unsigned short*)carve((size_t)5 * 2 * C * C * 2);
    unsigned short* Gp     = (unsigned short*)carve((size_t)NN * C * 2);
    unsigned short* Gn     = (unsigned short*)carve((size_t)NN * C * 2);
    unsigned short* P0     = (unsigned short*)carve((size_t)NN * C * 2);
    unsigned short* P1     = (unsigned short*)carve((size_t)NN * C * 2);
    unsigned short* P2     = (unsigned short*)carve((size_t)NN * C * 2);

    unsigned short* Wh[5], *Wl[5];
    for (int m = 0; m < 5; ++m) {
        Wh[m] = wt + (size_t)(2 * m) * C * C;
        Wl[m] = wt + (size_t)(2 * m + 1) * C * C;
    }

    hipMemsetAsync(cnt, 0, (size_t)(NN + 1) * 4, stream);
    hipMemsetAsync(sumbuf, 0, 512, stream);

    int gE = (EE + 255) / 256, gN = (NN + 255) / 256;

    // graph build
    k_hist <<<gE, 256, 0, stream>>>(ei, cnt);
    k_scan1<<<NB, 256, 0, stream>>>(cnt, bsum);
    k_scan2<<<1, 64, 0, stream>>>(bsum, total);
    k_scan3<<<NB, 256, 0, stream>>>(cnt, bsum, total, cnt, cursor);   // cnt := off
    k_fill <<<gE, 256, 0, stream>>>(ei, ew, cursor, em);
    k_dinv_csr<<<gN, 256, 0, stream>>>(cnt, em, dinv);
    k_scale<<<gN, 256, 0, stream>>>(cnt, dinv, em);

    // weight split/transpose
    k_wsplit<<<320, 256, 0, stream>>>(W1, W2, W3, W4, Wc, wt);

    int gM = (NN + 63) / 64;      // 782 blocks per chain (mm)
    int gA = (NN + 7) / 8;        // 6250 blocks per chain (agg: 8 nodes/block)

    // Layer 1: G1 = x@W1 shared by pos & neg ((xW1)[perm] == (x[perm])W1)
    k_mm_f32<<<gM, 256, 0, stream>>>(x, Wh[0], Wl[0], Gp);
    k_agg2<<<2 * gA, 256, 0, stream>>>(Gp, Gp, perm, dinv, cnt, em, b1, nullptr,
                                       P0, P1, nullptr, nullptr, gA);
    // Layers 2-3 (dual-chain)
    k_mm2 <<<2 * gM, 256, 0, stream>>>(P0, P1, Wh[1], Wl[1], Gp, Gn, gM);
    k_agg2<<<2 * gA, 256, 0, stream>>>(Gp, Gn, nullptr, dinv, cnt, em, b2, nullptr,
                                       P0, P1, nullptr, nullptr, gA);
    k_mm2 <<<2 * gM, 256, 0, stream>>>(P0, P1, Wh[2], Wl[2], Gp, Gn, gM);
    k_agg2<<<2 * gA, 256, 0, stream>>>(Gp, Gn, nullptr, dinv, cnt, em, b3, nullptr,
                                       P0, P1, nullptr, nullptr, gA);
    // Layer 4 (PReLU; pos writes f32 + plane for decoder, neg writes f32)
    k_mm2 <<<2 * gM, 256, 0, stream>>>(P0, P1, Wh[3], Wl[3], Gp, Gn, gM);
    k_agg2<<<2 * gA, 256, 0, stream>>>(Gp, Gn, nullptr, dinv, cnt, em, b4, prelu_a,
                                       P2, nullptr, pos_z, neg_z, gA);
    // Decoder: xout = Â(pos_z@Wc) + bc
    k_mm2 <<<gM, 256, 0, stream>>>(P2, P2, Wh[4], Wl[4], Gp, Gn, gM);
    k_agg2<<<gA, 256, 0, stream>>>(Gp, Gp, nullptr, dinv, cnt, em, bc, nullptr,
                                   nullptr, nullptr, xout, nullptr, gA);

    // summary
    k_sum<<<256, 256, 0, stream>>>(pos_z, sumbuf);
    k_summary<<<1, 128, 0, stream>>>(sumbuf, summary);

    // q soft assignment
    k_q<<<(NN + 63) / 64, 256, 0, stream>>>(xout, mu, qout);
}